// Round 8
// baseline (412.012 us; speedup 1.0000x reference)
//
#include <hip/hip_runtime.h>

#define NN 4096
#define EE 131072
#define NP1 2048
#define NP2 1024

typedef __attribute__((ext_vector_type(8))) __bf16 bf16x8;
typedef __attribute__((ext_vector_type(4))) float f32x4;
typedef __attribute__((ext_vector_type(8))) unsigned short ushort8;

static __device__ inline unsigned short bfbits(__bf16 b) {
  union { __bf16 x; unsigned short u; } c; c.x = b; return c.u;
}
static __device__ inline void split2(float v, unsigned short& h, unsigned short& l) {
  __bf16 hb = (__bf16)v;
  float hf = (float)hb;
  __bf16 lb = (__bf16)(v - hf);
  h = bfbits(hb); l = bfbits(lb);
}

// Packed fragment layout for [R rows][K k] bf16 (R%16==0, K%32==0):
// 16x32 tile (rt,kt); chunk-in-tile = ((k>>3)&3)*16 + (r&15) == MFMA lane id.
static __device__ inline size_t pchunk(int r, int k, int NT) {
  return ((size_t)(r >> 4) * NT + (k >> 5)) * 64 + (((k >> 3) & 3) << 4) + (r & 15);
}

// ---------------- graph build ----------------

__global__ void hist_kernel(const int* __restrict__ src, const int* __restrict__ dst,
                            int* __restrict__ cnt_src, int* __restrict__ cnt_dst, int E) {
  int e = blockIdx.x * blockDim.x + threadIdx.x;
  if (e < E) {
    atomicAdd(&cnt_src[src[e]], 1);
    atomicAdd(&cnt_dst[dst[e]], 1);
  }
}

// both exclusive scans in one launch; block 0 also emits dis0
__global__ __launch_bounds__(1024) void scan2(const int* __restrict__ cnt_dst,
                                              const int* __restrict__ cnt_src,
                                              int* __restrict__ csc_off, int* __restrict__ csr_off,
                                              float* __restrict__ dis0, int n) {
  __shared__ int tmp[4096];
  const int* in = blockIdx.x ? cnt_src : cnt_dst;
  int* out = blockIdx.x ? csr_off : csc_off;
  int tid = threadIdx.x;
  for (int i = tid; i < n; i += 1024) {
    int v = in[i];
    tmp[i] = v;
    if (blockIdx.x == 0) dis0[i] = rsqrtf((float)v + 1.0f);
  }
  __syncthreads();
  for (int off = 1; off < n; off <<= 1) {
    int v[4];
    int c = 0;
    for (int i = tid; i < n; i += 1024) { v[c++] = (i >= off) ? tmp[i - off] : 0; }
    __syncthreads();
    c = 0;
    for (int i = tid; i < n; i += 1024) { tmp[i] += v[c++]; }
    __syncthreads();
  }
  for (int i = tid; i < n; i += 1024) out[i + 1] = tmp[i];
  if (tid == 0) out[0] = 0;
}

__global__ void scatter_kernel(const int* __restrict__ src, const int* __restrict__ dst,
                               const int* __restrict__ csc_off, const int* __restrict__ csr_off,
                               int* __restrict__ fill_dst, int* __restrict__ fill_src,
                               int* __restrict__ csc_src, int* __restrict__ csr_dst, int E) {
  int e = blockIdx.x * blockDim.x + threadIdx.x;
  if (e < E) {
    int s = src[e], d = dst[e];
    int p = atomicAdd(&fill_dst[d], 1);
    csc_src[csc_off[d] + p] = s;
    int q = atomicAdd(&fill_src[s], 1);
    csr_dst[csr_off[s] + q] = d;
  }
}

// both p-norms in one launch (blockIdx 0 -> p0/256, 1 -> p1/512)
__global__ void pnorm2(const float* __restrict__ p0, const float* __restrict__ p1,
                       float* __restrict__ outv) {
  const float* p = blockIdx.x ? p1 : p0;
  int C = blockIdx.x ? 512 : 256;
  int tid = threadIdx.x;
  float acc = 0.f;
  for (int j = tid; j < C; j += 256) { float v = p[j]; acc += v * v; }
  for (int o = 32; o > 0; o >>= 1) acc += __shfl_down(acc, o);
  __shared__ float red[4];
  if ((tid & 63) == 0) red[tid >> 6] = acc;
  __syncthreads();
  if (tid == 0) outv[blockIdx.x] = sqrtf(red[0] + red[1] + red[2] + red[3]);
}

// ---------------- scoring / topk ----------------

__global__ void score_key(const float* __restrict__ X, const float* __restrict__ p,
                          const float* __restrict__ pn, float* __restrict__ s,
                          unsigned long long* __restrict__ keys, int C) {
  int i = blockIdx.x;
  int tid = threadIdx.x;
  float acc = 0.f;
  for (int j = tid; j < C; j += 256) acc += X[(size_t)i * C + j] * p[j];
  for (int o = 32; o > 0; o >>= 1) acc += __shfl_down(acc, o);
  __shared__ float red[4];
  if ((tid & 63) == 0) red[tid >> 6] = acc;
  __syncthreads();
  if (tid == 0) {
    float sv = tanhf((red[0] + red[1] + red[2] + red[3]) / pn[0]);
    s[i] = sv;
    unsigned u = __float_as_uint(sv);
    unsigned m = (u & 0x80000000u) ? ~u : (u | 0x80000000u);
    keys[i] = (((unsigned long long)(~m)) << 32) | (unsigned)i;  // desc value, asc index
  }
}

// full rank per candidate (streams all keys; no atomics), then place; optional cntk init
__global__ __launch_bounds__(256) void rank_full(const unsigned long long* __restrict__ keys,
                                                 const float* __restrict__ s, int n, int k,
                                                 int* __restrict__ kept, int* __restrict__ perm,
                                                 float* __restrict__ vals, int* __restrict__ cntk) {
  __shared__ unsigned long long kk[512];
  int cand = blockIdx.x * 256 + threadIdx.x;
  unsigned long long kc = keys[cand];
  int r = 0;
  for (int base = 0; base < n; base += 512) {
    kk[threadIdx.x] = keys[base + threadIdx.x];
    kk[threadIdx.x + 256] = keys[base + 256 + threadIdx.x];
    __syncthreads();
#pragma unroll 8
    for (int t = 0; t < 512; ++t) r += (kk[t] < kc) ? 1 : 0;
    __syncthreads();
  }
  int isk = (r < k) ? 1 : 0;
  if (isk) { perm[r] = cand; vals[r] = s[cand]; kept[cand] = r; }
  else kept[cand] = -1;
  if (cntk) cntk[cand] = isk;
}

// pooled row gather + gate + bf16 split into PACKED layout
__global__ void pool_split_p(const float* __restrict__ X, const int* __restrict__ perm,
                             const float* __restrict__ vals, unsigned short* __restrict__ h,
                             unsigned short* __restrict__ l, int C) {
  int a = blockIdx.x;
  int r = perm[a];
  float v = vals[a];
  int NT = C >> 5;
  for (int j0 = threadIdx.x * 8; j0 < C; j0 += 64 * 8) {
    ushort8 hv, lv;
#pragma unroll
    for (int e = 0; e < 8; ++e) {
      unsigned short he, le;
      split2(X[(size_t)r * C + j0 + e] * v, he, le);
      hv[e] = he; lv[e] = le;
    }
    size_t c = pchunk(a, j0, NT);
    *(ushort8*)&h[c * 8] = hv;
    *(ushort8*)&l[c * 8] = lv;
  }
}

// ---------------- augment 0: sparse 2-path rows, packed bf16 output ----------------

__global__ __launch_bounds__(256) void aug_row_p(const int* __restrict__ csr_off,
                                                 const int* __restrict__ csr_dst,
                                                 const int* __restrict__ kept,
                                                 const int* __restrict__ perm,
                                                 unsigned short* __restrict__ rm) {
  __shared__ float acc[NP1];
  int ki = blockIdx.x;
  int r = perm[ki];
  for (int t = threadIdx.x; t < NP1; t += 256) acc[t] = 0.f;
  __syncthreads();
  int s = csr_off[r], e = csr_off[r + 1];
  int nm = e - s;
  int wave = threadIdx.x >> 6, lane = threadIdx.x & 63;
  for (int m = wave; m <= nm; m += 4) {
    int k = (m < nm) ? csr_dst[s + m] : r;
    int s2 = csr_off[k], e2 = csr_off[k + 1];
    int n2 = e2 - s2;
    for (int t = lane; t <= n2; t += 64) {
      int j = (t < n2) ? csr_dst[s2 + t] : k;
      int kj = kept[j];
      if (kj >= 0) atomicAdd(&acc[kj], 1.0f);
    }
  }
  __syncthreads();
  if (threadIdx.x == 0) acc[ki] += 1.0f;  // +I on pooled graph
  __syncthreads();
  // packed bf16 write: chunk c = tid covers k = c*8..c*8+7 (exact small ints)
  int tid = threadIdx.x;
  ushort8 hv;
#pragma unroll
  for (int e8 = 0; e8 < 8; ++e8) hv[e8] = bfbits((__bf16)acc[tid * 8 + e8]);
  size_t dst = (((size_t)(ki >> 4)) * 64 + (tid >> 2)) * 64 + (size_t)(tid & 3) * 16 + (ki & 15);
  *(ushort8*)&rm[dst * 8] = hv;
}

// cntk[d] += [kept src] per edge occurrence (init by rank_full)
__global__ void cnt_edges(const int* __restrict__ src, const int* __restrict__ dst,
                          const int* __restrict__ kept, int* __restrict__ cntk, int E) {
  int e = blockIdx.x * blockDim.x + threadIdx.x;
  if (e < E && kept[src[e]] >= 0) atomicAdd(&cntk[dst[e]], 1);
}

// deg1[c] = 1 + cntk[perm[c]] + sum_{s in in(perm[c])} cntk[s]; writes dis1 directly
__global__ __launch_bounds__(256) void deg_gather(const int* __restrict__ csc_off,
                                                  const int* __restrict__ csc_src,
                                                  const int* __restrict__ cntk,
                                                  const int* __restrict__ perm,
                                                  float* __restrict__ dis) {
  int wid = threadIdx.x >> 6, lane = threadIdx.x & 63;
  int c = blockIdx.x * 4 + wid;
  int r = perm[c];
  int s = csc_off[r], e = csc_off[r + 1];
  int sum = 0;
  for (int t = s + lane; t < e; t += 64) sum += cntk[csc_src[t]];
  for (int o = 32; o > 0; o >>= 1) sum += __shfl_down(sum, o);
  if (lane == 0) dis[c] = rsqrtf((float)(sum + cntk[r] + 1));
}

// packed bf16 [n][n] -> packed bf16 transpose (exact)
__global__ __launch_bounds__(256) void t_pack(const unsigned short* __restrict__ in,
                                              unsigned short* __restrict__ outp, int n) {
  __shared__ unsigned short t[64][72];
  int r0 = blockIdx.y * 64, c0 = blockIdx.x * 64;
  int NT = n >> 5;
  for (int q = threadIdx.x; q < 512; q += 256) {
    int lt = q >> 6, l = q & 63;
    int rt = lt >> 1, kt2 = lt & 1;
    int r = rt * 16 + (l & 15), k = kt2 * 32 + (l >> 4) * 8;
    ushort8 v = *(const ushort8*)&in[pchunk(r0 + r, c0 + k, NT) * 8];
    *(ushort8*)&t[r][k] = v;
  }
  __syncthreads();
  for (int q = threadIdx.x; q < 512; q += 256) {
    int lt = q >> 6, l = q & 63;
    int jt = lt >> 1, kt2 = lt & 1;
    int j = jt * 16 + (l & 15), k = kt2 * 32 + (l >> 4) * 8;
    ushort8 v;
#pragma unroll
    for (int e = 0; e < 8; ++e) v[e] = t[k + e][j];
    *(ushort8*)&outp[pchunk(c0 + j, r0 + k, NT) * 8] = v;
  }
}

__global__ void dis_from_deg(const float* __restrict__ deg, float* __restrict__ dis, int n) {
  int i = blockIdx.x * blockDim.x + threadIdx.x;
  if (i < n) dis[i] = rsqrtf(deg[i]);
}

// ---------------- conversions ----------------

__global__ void split_p(const float* __restrict__ in, unsigned short* __restrict__ h,
                        unsigned short* __restrict__ l, int K) {
  int c = blockIdx.x * blockDim.x + threadIdx.x;
  int lane = c & 63, tile = c >> 6;
  int NT = K >> 5;
  int kt = tile % NT, rt = tile / NT;
  int r = rt * 16 + (lane & 15);
  int k = kt * 32 + (lane >> 4) * 8;
  const float* p = in + (size_t)r * K + k;
  ushort8 hv, lv;
#pragma unroll
  for (int e = 0; e < 8; ++e) {
    unsigned short he, le;
    split2(p[e], he, le);
    hv[e] = he; lv[e] = le;
  }
  *(ushort8*)&h[(size_t)c * 8] = hv;
  *(ushort8*)&l[(size_t)c * 8] = lv;
}

static __device__ inline void tsplit_body(const float* in, unsigned short* oh, unsigned short* ol,
                                          int R, int C, int c) {
  int lane = c & 63, tile = c >> 6;
  int NT = R >> 5;
  int kt = tile % NT, jt = tile / NT;
  int j = jt * 16 + (lane & 15);
  int k = kt * 32 + (lane >> 4) * 8;
  ushort8 hv, lv;
#pragma unroll
  for (int e = 0; e < 8; ++e) {
    unsigned short he, le;
    split2(in[(size_t)(k + e) * C + j], he, le);
    hv[e] = he; lv[e] = le;
  }
  *(ushort8*)&oh[(size_t)c * 8] = hv;
  *(ushort8*)&ol[(size_t)c * 8] = lv;
}

__global__ void tsplit_p(const float* __restrict__ in, unsigned short* __restrict__ oh,
                         unsigned short* __restrict__ ol, int R, int C) {
  int c = blockIdx.x * blockDim.x + threadIdx.x;
  tsplit_body(in, oh, ol, R, C, c);
}

// all five weight transpose-splits in one launch
__global__ void wconv_all(const float* w0, const float* w1, const float* w2,
                          const float* w3, const float* w4,
                          unsigned short* o0h, unsigned short* o0l,
                          unsigned short* o1h, unsigned short* o1l,
                          unsigned short* o2h, unsigned short* o2l,
                          unsigned short* o3h, unsigned short* o3l,
                          unsigned short* o4h, unsigned short* o4l) {
  int g = blockIdx.x * blockDim.x + threadIdx.x;
  if (g < 4096)        tsplit_body(w0, o0h, o0l, 128, 256, g);
  else if (g < 20480)  tsplit_body(w1, o1h, o1l, 256, 512, g - 4096);
  else if (g < 53248)  tsplit_body(w2, o2h, o2l, 512, 512, g - 20480);
  else if (g < 69632)  tsplit_body(w3, o3h, o3l, 512, 256, g - 53248);
  else                 tsplit_body(w4, o4h, o4l, 256, 128, g - 69632);
}

__global__ void gather_p(const unsigned short* __restrict__ in, const int* __restrict__ perm,
                         unsigned short* __restrict__ outp, int NT) {
  int c = blockIdx.x * blockDim.x + threadIdx.x;
  int lane = c & 63, tile = c >> 6;
  int kt = tile % NT, at = tile / NT;
  int a = at * 16 + (lane & 15);
  int sub = lane >> 4;
  int p = perm[a];
  size_t sc = ((size_t)(p >> 4) * NT + kt) * 64 + sub * 16 + (p & 15);
  *(ushort8*)&outp[(size_t)c * 8] = *(const ushort8*)&in[sc * 8];
}

__global__ void unpool_split_p(const float* __restrict__ res, const float* __restrict__ up,
                               const int* __restrict__ kept, unsigned short* __restrict__ h,
                               unsigned short* __restrict__ l, int C) {
  int c = blockIdx.x * blockDim.x + threadIdx.x;
  int lane = c & 63, tile = c >> 6;
  int NT = C >> 5;
  int kt = tile % NT, rt = tile / NT;
  int r = rt * 16 + (lane & 15);
  int j0 = kt * 32 + (lane >> 4) * 8;
  int kv = kept[r];
  ushort8 hv, lv;
#pragma unroll
  for (int e = 0; e < 8; ++e) {
    float v = res[(size_t)r * C + j0 + e];
    if (kv >= 0) v += up[(size_t)kv * C + j0 + e];
    unsigned short he, le;
    split2(v, he, le);
    hv[e] = he; lv[e] = le;
  }
  *(ushort8*)&h[(size_t)c * 8] = hv;
  *(ushort8*)&l[(size_t)c * 8] = lv;
}

// ---------------- misc ----------------

template <int C>
__global__ __launch_bounds__(256) void spmm_gather_v(const float* __restrict__ Y,
                                                     const int* __restrict__ off,
                                                     const int* __restrict__ srcs,
                                                     const float* __restrict__ dis,
                                                     const float* __restrict__ bias,
                                                     float* __restrict__ out) {
  constexpr int VEC = C / 64;
  int w = threadIdx.x >> 6, lane = threadIdx.x & 63;
  int c = blockIdx.x * 4 + w;
  int j = lane * VEC;
  float acc[VEC];
  const float* p = Y + (size_t)c * C + j;
#pragma unroll
  for (int u = 0; u < VEC; ++u) acc[u] = p[u];
  int s = off[c], e = off[c + 1];
  for (int t = s; t < e; ++t) {
    const float* q = Y + (size_t)srcs[t] * C + j;
#pragma unroll
    for (int u = 0; u < VEC; ++u) acc[u] += q[u];
  }
  float d = dis[c];
  float* o = out + (size_t)c * C + j;
#pragma unroll
  for (int u = 0; u < VEC; ++u) o[u] = fmaxf(d * acc[u] + bias[j + u], 0.0f);
}

template <int S>
__global__ void ep3(const float* __restrict__ p, const float* __restrict__ rs,
                    const float* __restrict__ bias, float* __restrict__ outp, int M, int N) {
  int idx = blockIdx.x * blockDim.x + threadIdx.x;
  int j4 = (idx * 4) % N, i = (idx * 4) / N;
  float4 a = {0.f, 0.f, 0.f, 0.f};
#pragma unroll
  for (int s = 0; s < S; ++s) {
    float4 b = *(const float4*)(p + ((size_t)s * M + i) * N + j4);
    a.x += b.x; a.y += b.y; a.z += b.z; a.w += b.w;
  }
  float r = rs[i];
  float4 o;
  o.x = fmaxf(r * a.x + bias[j4 + 0], 0.f);
  o.y = fmaxf(r * a.y + bias[j4 + 1], 0.f);
  o.z = fmaxf(r * a.z + bias[j4 + 2], 0.f);
  o.w = fmaxf(r * a.w + bias[j4 + 3], 0.f);
  *(float4*)(outp + (size_t)i * N + j4) = o;
}

// combine S partials (+I) -> B2 fp32, and accumulate column sums into deg
template <int S>
__global__ void ep_aug_cs(const float* __restrict__ p, float* __restrict__ B,
                          float* __restrict__ deg, int n) {
  int c = blockIdx.x * 256 + threadIdx.x;
  int r0 = blockIdx.y * 64;
  float cs = 0.f;
  for (int r = r0; r < r0 + 64; ++r) {
    float v = 0.f;
#pragma unroll
    for (int s = 0; s < S; ++s) v += p[((size_t)s * n + r) * n + c];
    if (r == c) v += 1.0f;
    B[(size_t)r * n + c] = v;
    cs += v;
  }
  atomicAdd(&deg[c], cs);
}

// ---------------- bf16-split MFMA GEMM, 32x32/wave ----------------
template <int EPI, int AL, int BL, int KK, int S>
__global__ __launch_bounds__(256) void gemm16(
    const unsigned short* __restrict__ Ah, const unsigned short* __restrict__ Al,
    const unsigned short* __restrict__ Bh, const unsigned short* __restrict__ Bl,
    int M, int N, const float* __restrict__ rs,
    float* __restrict__ C, unsigned short* __restrict__ Th, unsigned short* __restrict__ Tl) {
  static_assert(KK % 32 == 0, "K");
  constexpr int KSTEPS = KK / 32;
  const int NT = (KK * S) >> 5;
  const int gx = gridDim.x;
  int id = blockIdx.y * gx + blockIdx.x;
  int cpx = (gx * gridDim.y) >> 3;
  int sid = (id & 7) * cpx + (id >> 3);
  const int bx = sid % gx, by = sid / gx;
  const int z = (S > 1) ? blockIdx.z : 0;
  const int wid = threadIdx.x >> 6, lane = threadIdx.x & 63;
  const int i0 = by * 64 + (wid >> 1) * 32;
  const int j0 = bx * 64 + (wid & 1) * 32;
  const int lr = lane & 15, lk = lane >> 4;
  size_t aoff[2], boff[2];
#pragma unroll
  for (int t = 0; t < 2; ++t) {
    aoff[t] = ((size_t)((i0 >> 4) + t) * NT + z * (KK >> 5)) * 512 + lane * 8;
    boff[t] = ((size_t)((j0 >> 4) + t) * NT + z * (KK >> 5)) * 512 + lane * 8;
  }
  const f32x4 zf = {0.f, 0.f, 0.f, 0.f};
  f32x4 acc[2][2];
  acc[0][0] = zf; acc[0][1] = zf; acc[1][0] = zf; acc[1][1] = zf;

  bf16x8 ahf[4][2], bhf[4][2], alf[4][2], blf[4][2];
  auto loadk = [&](int kk, int b) {
    size_t o = (size_t)kk * 512;
    ahf[b][0] = *(const bf16x8*)(Ah + aoff[0] + o);
    ahf[b][1] = *(const bf16x8*)(Ah + aoff[1] + o);
    bhf[b][0] = *(const bf16x8*)(Bh + boff[0] + o);
    bhf[b][1] = *(const bf16x8*)(Bh + boff[1] + o);
    if constexpr (AL) {
      alf[b][0] = *(const bf16x8*)(Al + aoff[0] + o);
      alf[b][1] = *(const bf16x8*)(Al + aoff[1] + o);
    }
    if constexpr (BL) {
      blf[b][0] = *(const bf16x8*)(Bl + boff[0] + o);
      blf[b][1] = *(const bf16x8*)(Bl + boff[1] + o);
    }
  };
  auto domm = [&](int b) {
#pragma unroll
    for (int am = 0; am < 2; ++am)
#pragma unroll
      for (int bn = 0; bn < 2; ++bn) {
        acc[am][bn] = __builtin_amdgcn_mfma_f32_16x16x32_bf16(ahf[b][am], bhf[b][bn], acc[am][bn], 0, 0, 0);
        if constexpr (BL)
          acc[am][bn] = __builtin_amdgcn_mfma_f32_16x16x32_bf16(ahf[b][am], blf[b][bn], acc[am][bn], 0, 0, 0);
        if constexpr (AL)
          acc[am][bn] = __builtin_amdgcn_mfma_f32_16x16x32_bf16(alf[b][am], bhf[b][bn], acc[am][bn], 0, 0, 0);
      }
  };

  loadk(0, 0);
  if constexpr (KSTEPS > 1) loadk(1, 1);
  if constexpr (KSTEPS > 2) loadk(2, 2);
#pragma unroll
  for (int kk = 0; kk < KSTEPS; ++kk) {
    const int cur = kk & 3;
    if (kk + 3 < KSTEPS) loadk(kk + 3, (cur + 3) & 3);
    domm(cur);
  }

#pragma unroll
  for (int am = 0; am < 2; ++am)
#pragma unroll
    for (int bn = 0; bn < 2; ++bn) {
      int ib = i0 + 16 * am + lk * 4;
      int j = j0 + 16 * bn + lr;
      f32x4 a = acc[am][bn];
      if constexpr (S > 1) {
#pragma unroll
        for (int r = 0; r < 4; ++r) C[((size_t)z * M + ib + r) * N + j] = a[r];
      } else if constexpr (EPI == 0) {
#pragma unroll
        for (int r = 0; r < 4; ++r) C[(size_t)(ib + r) * N + j] = a[r];
      } else if constexpr (EPI == 1) {
#pragma unroll
        for (int r = 0; r < 4; ++r) C[(size_t)(ib + r) * N + j] = rs[ib + r] * a[r];
      } else {
        unsigned long long hp = 0, lp = 0;
#pragma unroll
        for (int r = 0; r < 4; ++r) {
          unsigned short hv, lv;
          split2(rs[ib + r] * a[r], hv, lv);
          hp |= ((unsigned long long)hv) << (16 * r);
          lp |= ((unsigned long long)lv) << (16 * r);
        }
        size_t c = pchunk(j, ib, M >> 5);
        *(unsigned long long*)&Th[c * 8 + (ib & 7)] = hp;
        *(unsigned long long*)&Tl[c * 8 + (ib & 7)] = lp;
      }
    }
}

// ---------------- bf16-split MFMA GEMM, 64x64/wave (split-K partials) ----------------
template <int AL, int BL, int KK, int S>
__global__ __launch_bounds__(256) void gemm64(
    const unsigned short* __restrict__ Ah, const unsigned short* __restrict__ Al,
    const unsigned short* __restrict__ Bh, const unsigned short* __restrict__ Bl,
    int M, int N, float* __restrict__ C) {
  static_assert(KK % 32 == 0, "K");
  constexpr int KSTEPS = KK / 32;
  const int NT = (KK * S) >> 5;
  const int gx = gridDim.x;
  int id = blockIdx.y * gx + blockIdx.x;
  int cpx = (gx * gridDim.y) >> 3;
  int sid = (id & 7) * cpx + (id >> 3);
  const int bx = sid % gx, by = sid / gx;
  const int z = blockIdx.z;
  const int wid = threadIdx.x >> 6, lane = threadIdx.x & 63;
  const int i0 = by * 128 + (wid >> 1) * 64;
  const int j0 = bx * 128 + (wid & 1) * 64;
  const int lr = lane & 15, lk = lane >> 4;
  size_t aoff[4], boff[4];
#pragma unroll
  for (int t = 0; t < 4; ++t) {
    aoff[t] = ((size_t)((i0 >> 4) + t) * NT + z * (KK >> 5)) * 512 + lane * 8;
    boff[t] = ((size_t)((j0 >> 4) + t) * NT + z * (KK >> 5)) * 512 + lane * 8;
  }
  const f32x4 zf = {0.f, 0.f, 0.f, 0.f};
  f32x4 acc[4][4];
#pragma unroll
  for (int a = 0; a < 4; ++a)
#pragma unroll
    for (int b = 0; b < 4; ++b) acc[a][b] = zf;

  bf16x8 ahf[2][4], bhf[2][4], alf[2][4], blf[2][4];
  auto loadk = [&](int kk, int b) {
    size_t o = (size_t)kk * 512;
#pragma unroll
    for (int t = 0; t < 4; ++t) {
      ahf[b][t] = *(const bf16x8*)(Ah + aoff[t] + o);
      bhf[b][t] = *(const bf16x8*)(Bh + boff[t] + o);
      if constexpr (AL) alf[b][t] = *(const bf16x8*)(Al + aoff[t] + o);
      if constexpr (BL) blf[b][t] = *(const bf16x8*)(Bl + boff[t] + o);
    }
  };
  auto domm = [&](int b) {
#pragma unroll
    for (int am = 0; am < 4; ++am)
#pragma unroll
      for (int bn = 0; bn < 4; ++bn) {
        acc[am][bn] = __builtin_amdgcn_mfma_f32_16x16x32_bf16(ahf[b][am], bhf[b][bn], acc[am][bn], 0, 0, 0);
        if constexpr (BL)
          acc[am][bn] = __builtin_amdgcn_mfma_f32_16x16x32_bf16(ahf[b][am], blf[b][bn], acc[am][bn], 0, 0, 0);
        if constexpr (AL)
          acc[am][bn] = __builtin_amdgcn_mfma_f32_16x16x32_bf16(alf[b][am], bhf[b][bn], acc[am][bn], 0, 0, 0);
      }
  };

  loadk(0, 0);
#pragma unroll
  for (int kk = 0; kk < KSTEPS; ++kk) {
    const int cur = kk & 1;
    if (kk + 1 < KSTEPS) loadk(kk + 1, cur ^ 1);
    domm(cur);
  }

#pragma unroll
  for (int am = 0; am < 4; ++am)
#pragma unroll
    for (int bn = 0; bn < 4; ++bn) {
      int ib = i0 + 16 * am + lk * 4;
      int j = j0 + 16 * bn + lr;
      f32x4 a = acc[am][bn];
#pragma unroll
      for (int r = 0; r < 4; ++r) C[((size_t)z * M + ib + r) * N + j] = a[r];
    }
}

// ---------------- launch ----------------

extern "C" void kernel_launch(void* const* d_in, const int* in_sizes, int n_in,
                              void* d_out, int out_size, void* d_ws, size_t ws_size,
                              hipStream_t stream) {
  (void)in_sizes; (void)n_in; (void)out_size; (void)ws_size;
  const float* x  = (const float*)d_in[0];
  const int* ei   = (const int*)d_in[1];
  const int* esrc = ei;
  const int* edst = ei + EE;
  const float* w0 = (const float*)d_in[2];
  const float* b0 = (const float*)d_in[3];
  const float* w1 = (const float*)d_in[4];
  const float* b1 = (const float*)d_in[5];
  const float* w2 = (const float*)d_in[6];
  const float* b2 = (const float*)d_in[7];
  const float* w3 = (const float*)d_in[8];
  const float* b3 = (const float*)d_in[9];
  const float* w4 = (const float*)d_in[10];
  const float* b4 = (const float*)d_in[11];
  const float* p0 = (const float*)d_in[12];
  const float* p1 = (const float*)d_in[13];
  float* out = (float*)d_out;

  char* ws = (char*)d_ws;
  size_t off = 0;
  auto alloc = [&](size_t b) { void* p = ws + off; off += (b + 255) & ~(size_t)255; return p; };

  int* csc_off = (int*)alloc(4 * (NN + 1));
  int* csr_off = (int*)alloc(4 * (NN + 1));
  int* csc_src = (int*)alloc(4 * EE);
  int* csr_dst = (int*)alloc(4 * EE);

  // zeroed region: 4 count arrays + deg2
  size_t zero_bytes = 4 * NN * 4 + 4 * NP2;
  int* cnts    = (int*)alloc(zero_bytes);
  int* cnt_dst = cnts;
  int* cnt_src = cnts + NN;
  int* fill_dst = cnts + 2 * NN;
  int* fill_src = cnts + 3 * NN;
  float* deg2 = (float*)(cnts + 4 * NN);

  int* cntk  = (int*)alloc(4 * NN);   // fully written by rank_full
  int* kept0 = (int*)alloc(4 * NN);
  int* perm0 = (int*)alloc(4 * NP1);
  int* kept1 = (int*)alloc(4 * NP1);
  int* perm1 = (int*)alloc(4 * NP2);
  float* dis0 = (float*)alloc(4 * NN);
  float* dis1 = (float*)alloc(4 * NP1);
  float* dis2 = (float*)alloc(4 * NP2);
  float* pnrm = (float*)alloc(8);
  float* s0   = (float*)alloc(4 * NN);
  float* vals0 = (float*)alloc(4 * NP1);
  float* s1   = (float*)alloc(4 * NP1);
  float* vals1 = (float*)alloc(4 * NP2);
  unsigned long long* keys0 = (unsigned long long*)alloc(8 * NN);
  unsigned long long* keys1 = (unsigned long long*)alloc(8 * NP1);

  const size_t MB = 1024 * 1024;
  // 16MB region: Gh/Hh gathers (0..8MB); later B2 fp32 (0..4MB) + B2t splits (4..8MB)
  char* regB1 = (char*)alloc(16 * MB);
  unsigned short* Gh = (unsigned short*)regB1;
  unsigned short* Hh = (unsigned short*)(regB1 + 4 * MB);
  float* B2   = (float*)regB1;
  unsigned short* B2th = (unsigned short*)(regB1 + 4 * MB);
  unsigned short* B2tl = (unsigned short*)(regB1 + 6 * MB);
  float* pscr = (float*)alloc(16 * MB);  // split-K partials

  unsigned short* B1rm = (unsigned short*)alloc(8 * MB);  // packed bf16 (exact)
  unsigned short* B1t  = (unsigned short*)alloc(8 * MB);  // packed bf16 transpose (exact)
  float* res0 = (float*)alloc(4 * MB);
  float* res1 = (float*)alloc(4 * MB);
  float* yreg = (float*)alloc(4 * MB);
  float* outreg = (float*)alloc(2 * MB);
  float* out2 = outreg, *out3 = outreg;
  char* ytreg = (char*)alloc(4 * MB);
  unsigned short* Y1th = (unsigned short*)ytreg;
  unsigned short* Y1tl = (unsigned short*)(ytreg + 2 * MB);
  unsigned short* Y2th = (unsigned short*)ytreg;
  unsigned short* Y2tl = (unsigned short*)(ytreg + 1 * MB);
  unsigned short* Y3th = (unsigned short*)ytreg;
  unsigned short* Y3tl = (unsigned short*)(ytreg + 1 * MB);
  char* xsreg = (char*)alloc(4 * MB);
  unsigned short* x3h = (unsigned short*)xsreg;
  unsigned short* x3l = (unsigned short*)(xsreg + 2 * MB);
  unsigned short* x4h = (unsigned short*)xsreg;
  unsigned short* x4l = (unsigned short*)(xsreg + 2 * MB);
  unsigned short* xh = (unsigned short*)alloc(1 * MB);
  unsigned short* xl = (unsigned short*)alloc(1 * MB);
  char* xsm = (char*)alloc(2 * MB);
  unsigned short* x1h = (unsigned short*)xsm;
  unsigned short* x1l = (unsigned short*)(xsm + 1 * MB);
  unsigned short* x2h = (unsigned short*)xsm;
  unsigned short* x2l = (unsigned short*)(xsm + 1 * MB);
  unsigned short* Wt0h = (unsigned short*)alloc(256 * 128 * 2);
  unsigned short* Wt0l = (unsigned short*)alloc(256 * 128 * 2);
  unsigned short* Wt1h = (unsigned short*)alloc(512 * 256 * 2);
  unsigned short* Wt1l = (unsigned short*)alloc(512 * 256 * 2);
  unsigned short* Wt2h = (unsigned short*)alloc(512 * 512 * 2);
  unsigned short* Wt2l = (unsigned short*)alloc(512 * 512 * 2);
  unsigned short* Wt3h = (unsigned short*)alloc(256 * 512 * 2);
  unsigned short* Wt3l = (unsigned short*)alloc(256 * 512 * 2);
  unsigned short* Wt4h = (unsigned short*)alloc(128 * 256 * 2);
  unsigned short* Wt4l = (unsigned short*)alloc(128 * 256 * 2);

  hipMemsetAsync(cnts, 0, zero_bytes, stream);

  // graph build (4 launches)
  hist_kernel<<<EE / 256, 256, 0, stream>>>(esrc, edst, cnt_src, cnt_dst, EE);
  scan2<<<2, 1024, 0, stream>>>(cnt_dst, cnt_src, csc_off, csr_off, dis0, NN);
  scatter_kernel<<<EE / 256, 256, 0, stream>>>(esrc, edst, csc_off, csr_off,
                                               fill_dst, fill_src, csc_src, csr_dst, EE);
  pnorm2<<<2, 256, 0, stream>>>(p0, p1, pnrm);

  // operand conversions (2 launches)
  wconv_all<<<288, 256, 0, stream>>>(w0, w1, w2, w3, w4, Wt0h, Wt0l, Wt1h, Wt1l,
                                     Wt2h, Wt2l, Wt3h, Wt3l, Wt4h, Wt4l);
  split_p<<<(NN * 128 / 8) / 256, 256, 0, stream>>>(x, xh, xl, 128);

  // gcn0
  gemm16<1, 1, 1, 128, 1><<<dim3(4, 64), 256, 0, stream>>>(xh, xl, Wt0h, Wt0l,
                                                           NN, 256, dis0, yreg, nullptr, nullptr);
  spmm_gather_v<256><<<NN / 4, 256, 0, stream>>>(yreg, csc_off, csc_src, dis0, b0, res0);

  // pool0
  score_key<<<NN, 256, 0, stream>>>(res0, p0, pnrm + 0, s0, keys0, 256);
  rank_full<<<NN / 256, 256, 0, stream>>>(keys0, s0, NN, NP1, kept0, perm0, vals0, cntk);
  pool_split_p<<<NP1, 64, 0, stream>>>(res0, perm0, vals0, x1h, x1l, 256);

  // augment0: packed B1rm directly, sparse deg, packed transpose
  aug_row_p<<<NP1, 256, 0, stream>>>(csr_off, csr_dst, kept0, perm0, B1rm);
  cnt_edges<<<EE / 256, 256, 0, stream>>>(esrc, edst, kept0, cntk, EE);
  deg_gather<<<NP1 / 4, 256, 0, stream>>>(csc_off, csc_src, cntk, perm0, dis1);
  t_pack<<<dim3(32, 32), 256, 0, stream>>>(B1rm, B1t, NP1);

  // gcn1
  gemm16<2, 1, 1, 256, 1><<<dim3(8, 32), 256, 0, stream>>>(x1h, x1l, Wt1h, Wt1l,
                                                           NP1, 512, dis1, nullptr, Y1th, Y1tl);
  gemm64<0, 1, 512, 4><<<dim3(4, 16, 4), 256, 0, stream>>>(B1t, nullptr, Y1th, Y1tl,
                                                           NP1, 512, pscr);
  ep3<4><<<(NP1 * 512) / 1024, 256, 0, stream>>>(pscr, dis1, b1, res1, NP1, 512);

  // pool1
  score_key<<<NP1, 256, 0, stream>>>(res1, p1, pnrm + 1, s1, keys1, 512);
  rank_full<<<NP1 / 256, 256, 0, stream>>>(keys1, s1, NP1, NP2, kept1, perm1, vals1, nullptr);
  pool_split_p<<<NP2, 64, 0, stream>>>(res1, perm1, vals1, x2h, x2l, 512);

  // augment1: gathered packed operands -> dense exact GEMM (split-K) -> B2 + colsums
  gather_p<<<(NP2 * NP1 / 8) / 256, 256, 0, stream>>>(B1rm, perm1, Gh, NP1 >> 5);
  gather_p<<<(NP2 * NP1 / 8) / 256, 256, 0, stream>>>(B1t, perm1, Hh, NP1 >> 5);
  gemm64<0, 0, 512, 4><<<dim3(8, 8, 4), 256, 0, stream>>>(Gh, nullptr, Hh, nullptr,
                                                          NP2, NP2, pscr);
  ep_aug_cs<4><<<dim3(NP2 / 256, NP2 / 64), 256, 0, stream>>>(pscr, B2, deg2, NP2);
  dis_from_deg<<<NP2 / 256, 256, 0, stream>>>(deg2, dis2, NP2);
  tsplit_p<<<(NP2 * NP2 / 8) / 256, 256, 0, stream>>>(B2, B2th, B2tl, NP2, NP2);

  // gcn2 (bottleneck)
  gemm16<2, 1, 1, 512, 1><<<dim3(8, 16), 256, 0, stream>>>(x2h, x2l, Wt2h, Wt2l,
                                                           NP2, 512, dis2, nullptr, Y2th, Y2tl);
  gemm16<0, 1, 1, 512, 2><<<dim3(8, 16, 2), 256, 0, stream>>>(B2th, B2tl, Y2th, Y2tl,
                                                              NP2, 512, nullptr, pscr, nullptr, nullptr);
  ep3<2><<<(NP2 * 512) / 1024, 256, 0, stream>>>(pscr, dis2, b2, out2, NP2, 512);

  // up1
  unpool_split_p<<<(NP1 * 512 / 8) / 256, 256, 0, stream>>>(res1, out2, kept1, x3h, x3l, 512);
  gemm16<2, 1, 1, 512, 1><<<dim3(4, 32), 256, 0, stream>>>(x3h, x3l, Wt3h, Wt3l,
                                                           NP1, 256, dis1, nullptr, Y3th, Y3tl);
  gemm64<0, 1, 256, 8><<<dim3(2, 16, 8), 256, 0, stream>>>(B1t, nullptr, Y3th, Y3tl,
                                                           NP1, 256, pscr);
  ep3<8><<<(NP1 * 256) / 1024, 256, 0, stream>>>(pscr, dis1, b3, out3, NP1, 256);

  // up0
  unpool_split_p<<<(NN * 256 / 8) / 256, 256, 0, stream>>>(res0, out3, kept0, x4h, x4l, 256);
  gemm16<1, 1, 1, 256, 1><<<dim3(2, 64), 256, 0, stream>>>(x4h, x4l, Wt4h, Wt4l,
                                                           NN, 128, dis0, yreg, nullptr, nullptr);
  spmm_gather_v<128><<<NN / 4, 256, 0, stream>>>(yreg, csc_off, csc_src, dis0, b4, out);
}

// Round 9
// 343.932 us; speedup vs baseline: 1.1979x; 1.1979x over previous
//
#include <hip/hip_runtime.h>

#define NN 4096
#define EE 131072
#define NP1 2048
#define NP2 1024

typedef __attribute__((ext_vector_type(8))) __bf16 bf16x8;
typedef __attribute__((ext_vector_type(4))) float f32x4;
typedef __attribute__((ext_vector_type(8))) unsigned short ushort8;

static __device__ inline unsigned short bfbits(__bf16 b) {
  union { __bf16 x; unsigned short u; } c; c.x = b; return c.u;
}
static __device__ inline void split2(float v, unsigned short& h, unsigned short& l) {
  __bf16 hb = (__bf16)v;
  float hf = (float)hb;
  __bf16 lb = (__bf16)(v - hf);
  h = bfbits(hb); l = bfbits(lb);
}

// Packed fragment layout for [R rows][K k] bf16 (R%16==0, K%32==0):
// 16x32 tile (rt,kt); chunk-in-tile = ((k>>3)&3)*16 + (r&15) == MFMA lane id.
static __device__ inline size_t pchunk(int r, int k, int NT) {
  return ((size_t)(r >> 4) * NT + (k >> 5)) * 64 + (((k >> 3) & 3) << 4) + (r & 15);
}

// ---------------- graph build ----------------

__global__ void hist_kernel(const int* __restrict__ src, const int* __restrict__ dst,
                            int* __restrict__ cnt_src, int* __restrict__ cnt_dst, int E) {
  int e = blockIdx.x * blockDim.x + threadIdx.x;
  if (e < E) {
    atomicAdd(&cnt_src[src[e]], 1);
    atomicAdd(&cnt_dst[dst[e]], 1);
  }
}

// both exclusive scans in one launch; block 0 also emits dis0
__global__ __launch_bounds__(1024) void scan2(const int* __restrict__ cnt_dst,
                                              const int* __restrict__ cnt_src,
                                              int* __restrict__ csc_off, int* __restrict__ csr_off,
                                              float* __restrict__ dis0, int n) {
  __shared__ int tmp[4096];
  const int* in = blockIdx.x ? cnt_src : cnt_dst;
  int* out = blockIdx.x ? csr_off : csc_off;
  int tid = threadIdx.x;
  for (int i = tid; i < n; i += 1024) {
    int v = in[i];
    tmp[i] = v;
    if (blockIdx.x == 0) dis0[i] = rsqrtf((float)v + 1.0f);
  }
  __syncthreads();
  for (int off = 1; off < n; off <<= 1) {
    int v[4];
    int c = 0;
    for (int i = tid; i < n; i += 1024) { v[c++] = (i >= off) ? tmp[i - off] : 0; }
    __syncthreads();
    c = 0;
    for (int i = tid; i < n; i += 1024) { tmp[i] += v[c++]; }
    __syncthreads();
  }
  for (int i = tid; i < n; i += 1024) out[i + 1] = tmp[i];
  if (tid == 0) out[0] = 0;
}

__global__ void scatter_kernel(const int* __restrict__ src, const int* __restrict__ dst,
                               const int* __restrict__ csc_off, const int* __restrict__ csr_off,
                               int* __restrict__ fill_dst, int* __restrict__ fill_src,
                               int* __restrict__ csc_src, int* __restrict__ csr_dst, int E) {
  int e = blockIdx.x * blockDim.x + threadIdx.x;
  if (e < E) {
    int s = src[e], d = dst[e];
    int p = atomicAdd(&fill_dst[d], 1);
    csc_src[csc_off[d] + p] = s;
    int q = atomicAdd(&fill_src[s], 1);
    csr_dst[csr_off[s] + q] = d;
  }
}

// both p-norms in one launch (blockIdx 0 -> p0/256, 1 -> p1/512)
__global__ void pnorm2(const float* __restrict__ p0, const float* __restrict__ p1,
                       float* __restrict__ outv) {
  const float* p = blockIdx.x ? p1 : p0;
  int C = blockIdx.x ? 512 : 256;
  int tid = threadIdx.x;
  float acc = 0.f;
  for (int j = tid; j < C; j += 256) { float v = p[j]; acc += v * v; }
  for (int o = 32; o > 0; o >>= 1) acc += __shfl_down(acc, o);
  __shared__ float red[4];
  if ((tid & 63) == 0) red[tid >> 6] = acc;
  __syncthreads();
  if (tid == 0) outv[blockIdx.x] = sqrtf(red[0] + red[1] + red[2] + red[3]);
}

// ---------------- scoring / topk ----------------

__global__ void score_key(const float* __restrict__ X, const float* __restrict__ p,
                          const float* __restrict__ pn, float* __restrict__ s,
                          unsigned long long* __restrict__ keys, int C) {
  int i = blockIdx.x;
  int tid = threadIdx.x;
  float acc = 0.f;
  for (int j = tid; j < C; j += 256) acc += X[(size_t)i * C + j] * p[j];
  for (int o = 32; o > 0; o >>= 1) acc += __shfl_down(acc, o);
  __shared__ float red[4];
  if ((tid & 63) == 0) red[tid >> 6] = acc;
  __syncthreads();
  if (tid == 0) {
    float sv = tanhf((red[0] + red[1] + red[2] + red[3]) / pn[0]);
    s[i] = sv;
    unsigned u = __float_as_uint(sv);
    unsigned m = (u & 0x80000000u) ? ~u : (u | 0x80000000u);
    keys[i] = (((unsigned long long)(~m)) << 32) | (unsigned)i;  // desc value, asc index
  }
}

// partial rank: block (bx,by) counts keys[by*512..+512) against candidates [bx*256..+256)
__global__ __launch_bounds__(256) void rank_count(const unsigned long long* __restrict__ keys,
                                                  int* __restrict__ rank) {
  __shared__ unsigned long long kk[512];
  int tid = threadIdx.x;
  int cand = blockIdx.x * 256 + tid;
  int base = blockIdx.y * 512;
  kk[tid] = keys[base + tid];
  kk[tid + 256] = keys[base + tid + 256];
  __syncthreads();
  unsigned long long kc = keys[cand];
  int c = 0;
#pragma unroll 8
  for (int t = 0; t < 512; ++t) c += (kk[t] < kc) ? 1 : 0;
  atomicAdd(&rank[cand], c);
}

// place by rank; optionally emit cntk (1 if kept) for the sparse-deg path
__global__ void rank_place(const float* __restrict__ s, const int* __restrict__ rank, int k, int n,
                           int* __restrict__ kept, int* __restrict__ perm, float* __restrict__ vals,
                           int* __restrict__ cntk) {
  int i = blockIdx.x * blockDim.x + threadIdx.x;
  if (i < n) {
    int r = rank[i];
    int isk = (r < k) ? 1 : 0;
    if (isk) { perm[r] = i; vals[r] = s[i]; kept[i] = r; }
    else kept[i] = -1;
    if (cntk) cntk[i] = isk;
  }
}

// pooled row gather + gate + bf16 split into PACKED layout
__global__ void pool_split_p(const float* __restrict__ X, const int* __restrict__ perm,
                             const float* __restrict__ vals, unsigned short* __restrict__ h,
                             unsigned short* __restrict__ l, int C) {
  int a = blockIdx.x;
  int r = perm[a];
  float v = vals[a];
  int NT = C >> 5;
  for (int j0 = threadIdx.x * 8; j0 < C; j0 += 64 * 8) {
    ushort8 hv, lv;
#pragma unroll
    for (int e = 0; e < 8; ++e) {
      unsigned short he, le;
      split2(X[(size_t)r * C + j0 + e] * v, he, le);
      hv[e] = he; lv[e] = le;
    }
    size_t c = pchunk(a, j0, NT);
    *(ushort8*)&h[c * 8] = hv;
    *(ushort8*)&l[c * 8] = lv;
  }
}

// ---------------- augment 0: sparse 2-path rows, packed bf16 output ----------------

__global__ __launch_bounds__(256) void aug_row_p(const int* __restrict__ csr_off,
                                                 const int* __restrict__ csr_dst,
                                                 const int* __restrict__ kept,
                                                 const int* __restrict__ perm,
                                                 unsigned short* __restrict__ rm) {
  __shared__ float acc[NP1];
  int ki = blockIdx.x;
  int r = perm[ki];
  for (int t = threadIdx.x; t < NP1; t += 256) acc[t] = 0.f;
  __syncthreads();
  int s = csr_off[r], e = csr_off[r + 1];
  int nm = e - s;
  int wave = threadIdx.x >> 6, lane = threadIdx.x & 63;
  for (int m = wave; m <= nm; m += 4) {
    int k = (m < nm) ? csr_dst[s + m] : r;
    int s2 = csr_off[k], e2 = csr_off[k + 1];
    int n2 = e2 - s2;
    for (int t = lane; t <= n2; t += 64) {
      int j = (t < n2) ? csr_dst[s2 + t] : k;
      int kj = kept[j];
      if (kj >= 0) atomicAdd(&acc[kj], 1.0f);
    }
  }
  __syncthreads();
  if (threadIdx.x == 0) acc[ki] += 1.0f;  // +I on pooled graph
  __syncthreads();
  // packed bf16 write: chunk c = tid covers k = c*8..c*8+7 (exact small ints)
  int tid = threadIdx.x;
  ushort8 hv;
#pragma unroll
  for (int e8 = 0; e8 < 8; ++e8) hv[e8] = bfbits((__bf16)acc[tid * 8 + e8]);
  size_t dst = (((size_t)(ki >> 4)) * 64 + (tid >> 2)) * 64 + (size_t)(tid & 3) * 16 + (ki & 15);
  *(ushort8*)&rm[dst * 8] = hv;
}

// cntk[d] += [kept src] per edge occurrence (init by rank_place)
__global__ void cnt_edges(const int* __restrict__ src, const int* __restrict__ dst,
                          const int* __restrict__ kept, int* __restrict__ cntk, int E) {
  int e = blockIdx.x * blockDim.x + threadIdx.x;
  if (e < E && kept[src[e]] >= 0) atomicAdd(&cntk[dst[e]], 1);
}

// deg1[c] = 1 + cntk[perm[c]] + sum_{s in in(perm[c])} cntk[s]; writes dis1 directly
__global__ __launch_bounds__(256) void deg_gather(const int* __restrict__ csc_off,
                                                  const int* __restrict__ csc_src,
                                                  const int* __restrict__ cntk,
                                                  const int* __restrict__ perm,
                                                  float* __restrict__ dis) {
  int wid = threadIdx.x >> 6, lane = threadIdx.x & 63;
  int c = blockIdx.x * 4 + wid;
  int r = perm[c];
  int s = csc_off[r], e = csc_off[r + 1];
  int sum = 0;
  for (int t = s + lane; t < e; t += 64) sum += cntk[csc_src[t]];
  for (int o = 32; o > 0; o >>= 1) sum += __shfl_down(sum, o);
  if (lane == 0) dis[c] = rsqrtf((float)(sum + cntk[r] + 1));
}

// packed bf16 [n][n] -> packed bf16 transpose (exact)
__global__ __launch_bounds__(256) void t_pack(const unsigned short* __restrict__ in,
                                              unsigned short* __restrict__ outp, int n) {
  __shared__ unsigned short t[64][72];
  int r0 = blockIdx.y * 64, c0 = blockIdx.x * 64;
  int NT = n >> 5;
  for (int q = threadIdx.x; q < 512; q += 256) {
    int lt = q >> 6, l = q & 63;
    int rt = lt >> 1, kt2 = lt & 1;
    int r = rt * 16 + (l & 15), k = kt2 * 32 + (l >> 4) * 8;
    ushort8 v = *(const ushort8*)&in[pchunk(r0 + r, c0 + k, NT) * 8];
    *(ushort8*)&t[r][k] = v;
  }
  __syncthreads();
  for (int q = threadIdx.x; q < 512; q += 256) {
    int lt = q >> 6, l = q & 63;
    int jt = lt >> 1, kt2 = lt & 1;
    int j = jt * 16 + (l & 15), k = kt2 * 32 + (l >> 4) * 8;
    ushort8 v;
#pragma unroll
    for (int e = 0; e < 8; ++e) v[e] = t[k + e][j];
    *(ushort8*)&outp[pchunk(c0 + j, r0 + k, NT) * 8] = v;
  }
}

__global__ void dis_from_deg(const float* __restrict__ deg, float* __restrict__ dis, int n) {
  int i = blockIdx.x * blockDim.x + threadIdx.x;
  if (i < n) dis[i] = rsqrtf(deg[i]);
}

// ---------------- conversions ----------------

__global__ void split_p(const float* __restrict__ in, unsigned short* __restrict__ h,
                        unsigned short* __restrict__ l, int K) {
  int c = blockIdx.x * blockDim.x + threadIdx.x;
  int lane = c & 63, tile = c >> 6;
  int NT = K >> 5;
  int kt = tile % NT, rt = tile / NT;
  int r = rt * 16 + (lane & 15);
  int k = kt * 32 + (lane >> 4) * 8;
  const float* p = in + (size_t)r * K + k;
  ushort8 hv, lv;
#pragma unroll
  for (int e = 0; e < 8; ++e) {
    unsigned short he, le;
    split2(p[e], he, le);
    hv[e] = he; lv[e] = le;
  }
  *(ushort8*)&h[(size_t)c * 8] = hv;
  *(ushort8*)&l[(size_t)c * 8] = lv;
}

static __device__ inline void tsplit_body(const float* in, unsigned short* oh, unsigned short* ol,
                                          int R, int C, int c) {
  int lane = c & 63, tile = c >> 6;
  int NT = R >> 5;
  int kt = tile % NT, jt = tile / NT;
  int j = jt * 16 + (lane & 15);
  int k = kt * 32 + (lane >> 4) * 8;
  ushort8 hv, lv;
#pragma unroll
  for (int e = 0; e < 8; ++e) {
    unsigned short he, le;
    split2(in[(size_t)(k + e) * C + j], he, le);
    hv[e] = he; lv[e] = le;
  }
  *(ushort8*)&oh[(size_t)c * 8] = hv;
  *(ushort8*)&ol[(size_t)c * 8] = lv;
}

__global__ void tsplit_p(const float* __restrict__ in, unsigned short* __restrict__ oh,
                         unsigned short* __restrict__ ol, int R, int C) {
  int c = blockIdx.x * blockDim.x + threadIdx.x;
  tsplit_body(in, oh, ol, R, C, c);
}

// all five weight transpose-splits in one launch
__global__ void wconv_all(const float* w0, const float* w1, const float* w2,
                          const float* w3, const float* w4,
                          unsigned short* o0h, unsigned short* o0l,
                          unsigned short* o1h, unsigned short* o1l,
                          unsigned short* o2h, unsigned short* o2l,
                          unsigned short* o3h, unsigned short* o3l,
                          unsigned short* o4h, unsigned short* o4l) {
  int g = blockIdx.x * blockDim.x + threadIdx.x;
  if (g < 4096)        tsplit_body(w0, o0h, o0l, 128, 256, g);
  else if (g < 20480)  tsplit_body(w1, o1h, o1l, 256, 512, g - 4096);
  else if (g < 53248)  tsplit_body(w2, o2h, o2l, 512, 512, g - 20480);
  else if (g < 69632)  tsplit_body(w3, o3h, o3l, 512, 256, g - 53248);
  else                 tsplit_body(w4, o4h, o4l, 256, 128, g - 69632);
}

__global__ void gather_p(const unsigned short* __restrict__ in, const int* __restrict__ perm,
                         unsigned short* __restrict__ outp, int NT) {
  int c = blockIdx.x * blockDim.x + threadIdx.x;
  int lane = c & 63, tile = c >> 6;
  int kt = tile % NT, at = tile / NT;
  int a = at * 16 + (lane & 15);
  int sub = lane >> 4;
  int p = perm[a];
  size_t sc = ((size_t)(p >> 4) * NT + kt) * 64 + sub * 16 + (p & 15);
  *(ushort8*)&outp[(size_t)c * 8] = *(const ushort8*)&in[sc * 8];
}

__global__ void unpool_split_p(const float* __restrict__ res, const float* __restrict__ up,
                               const int* __restrict__ kept, unsigned short* __restrict__ h,
                               unsigned short* __restrict__ l, int C) {
  int c = blockIdx.x * blockDim.x + threadIdx.x;
  int lane = c & 63, tile = c >> 6;
  int NT = C >> 5;
  int kt = tile % NT, rt = tile / NT;
  int r = rt * 16 + (lane & 15);
  int j0 = kt * 32 + (lane >> 4) * 8;
  int kv = kept[r];
  ushort8 hv, lv;
#pragma unroll
  for (int e = 0; e < 8; ++e) {
    float v = res[(size_t)r * C + j0 + e];
    if (kv >= 0) v += up[(size_t)kv * C + j0 + e];
    unsigned short he, le;
    split2(v, he, le);
    hv[e] = he; lv[e] = le;
  }
  *(ushort8*)&h[(size_t)c * 8] = hv;
  *(ushort8*)&l[(size_t)c * 8] = lv;
}

// ---------------- misc ----------------

template <int C>
__global__ __launch_bounds__(256) void spmm_gather_v(const float* __restrict__ Y,
                                                     const int* __restrict__ off,
                                                     const int* __restrict__ srcs,
                                                     const float* __restrict__ dis,
                                                     const float* __restrict__ bias,
                                                     float* __restrict__ out) {
  constexpr int VEC = C / 64;
  int w = threadIdx.x >> 6, lane = threadIdx.x & 63;
  int c = blockIdx.x * 4 + w;
  int j = lane * VEC;
  float acc[VEC];
  const float* p = Y + (size_t)c * C + j;
#pragma unroll
  for (int u = 0; u < VEC; ++u) acc[u] = p[u];
  int s = off[c], e = off[c + 1];
  for (int t = s; t < e; ++t) {
    const float* q = Y + (size_t)srcs[t] * C + j;
#pragma unroll
    for (int u = 0; u < VEC; ++u) acc[u] += q[u];
  }
  float d = dis[c];
  float* o = out + (size_t)c * C + j;
#pragma unroll
  for (int u = 0; u < VEC; ++u) o[u] = fmaxf(d * acc[u] + bias[j + u], 0.0f);
}

template <int S>
__global__ void ep3(const float* __restrict__ p, const float* __restrict__ rs,
                    const float* __restrict__ bias, float* __restrict__ outp, int M, int N) {
  int idx = blockIdx.x * blockDim.x + threadIdx.x;
  int j4 = (idx * 4) % N, i = (idx * 4) / N;
  float4 a = {0.f, 0.f, 0.f, 0.f};
#pragma unroll
  for (int s = 0; s < S; ++s) {
    float4 b = *(const float4*)(p + ((size_t)s * M + i) * N + j4);
    a.x += b.x; a.y += b.y; a.z += b.z; a.w += b.w;
  }
  float r = rs[i];
  float4 o;
  o.x = fmaxf(r * a.x + bias[j4 + 0], 0.f);
  o.y = fmaxf(r * a.y + bias[j4 + 1], 0.f);
  o.z = fmaxf(r * a.z + bias[j4 + 2], 0.f);
  o.w = fmaxf(r * a.w + bias[j4 + 3], 0.f);
  *(float4*)(outp + (size_t)i * N + j4) = o;
}

// combine S partials (+I) -> B2 fp32, and accumulate column sums into deg
template <int S>
__global__ void ep_aug_cs(const float* __restrict__ p, float* __restrict__ B,
                          float* __restrict__ deg, int n) {
  int c = blockIdx.x * 256 + threadIdx.x;
  int r0 = blockIdx.y * 64;
  float cs = 0.f;
  for (int r = r0; r < r0 + 64; ++r) {
    float v = 0.f;
#pragma unroll
    for (int s = 0; s < S; ++s) v += p[((size_t)s * n + r) * n + c];
    if (r == c) v += 1.0f;
    B[(size_t)r * n + c] = v;
    cs += v;
  }
  atomicAdd(&deg[c], cs);
}

// ---------------- bf16-split MFMA GEMM, 32x32/wave ----------------
template <int EPI, int AL, int BL, int KK, int S>
__global__ __launch_bounds__(256) void gemm16(
    const unsigned short* __restrict__ Ah, const unsigned short* __restrict__ Al,
    const unsigned short* __restrict__ Bh, const unsigned short* __restrict__ Bl,
    int M, int N, const float* __restrict__ rs,
    float* __restrict__ C, unsigned short* __restrict__ Th, unsigned short* __restrict__ Tl) {
  static_assert(KK % 32 == 0, "K");
  constexpr int KSTEPS = KK / 32;
  const int NT = (KK * S) >> 5;
  const int gx = gridDim.x;
  int id = blockIdx.y * gx + blockIdx.x;
  int cpx = (gx * gridDim.y) >> 3;
  int sid = (id & 7) * cpx + (id >> 3);
  const int bx = sid % gx, by = sid / gx;
  const int z = (S > 1) ? blockIdx.z : 0;
  const int wid = threadIdx.x >> 6, lane = threadIdx.x & 63;
  const int i0 = by * 64 + (wid >> 1) * 32;
  const int j0 = bx * 64 + (wid & 1) * 32;
  const int lr = lane & 15, lk = lane >> 4;
  size_t aoff[2], boff[2];
#pragma unroll
  for (int t = 0; t < 2; ++t) {
    aoff[t] = ((size_t)((i0 >> 4) + t) * NT + z * (KK >> 5)) * 512 + lane * 8;
    boff[t] = ((size_t)((j0 >> 4) + t) * NT + z * (KK >> 5)) * 512 + lane * 8;
  }
  const f32x4 zf = {0.f, 0.f, 0.f, 0.f};
  f32x4 acc[2][2];
  acc[0][0] = zf; acc[0][1] = zf; acc[1][0] = zf; acc[1][1] = zf;

  bf16x8 ahf[4][2], bhf[4][2], alf[4][2], blf[4][2];
  auto loadk = [&](int kk, int b) {
    size_t o = (size_t)kk * 512;
    ahf[b][0] = *(const bf16x8*)(Ah + aoff[0] + o);
    ahf[b][1] = *(const bf16x8*)(Ah + aoff[1] + o);
    bhf[b][0] = *(const bf16x8*)(Bh + boff[0] + o);
    bhf[b][1] = *(const bf16x8*)(Bh + boff[1] + o);
    if constexpr (AL) {
      alf[b][0] = *(const bf16x8*)(Al + aoff[0] + o);
      alf[b][1] = *(const bf16x8*)(Al + aoff[1] + o);
    }
    if constexpr (BL) {
      blf[b][0] = *(const bf16x8*)(Bl + boff[0] + o);
      blf[b][1] = *(const bf16x8*)(Bl + boff[1] + o);
    }
  };
  auto domm = [&](int b) {
#pragma unroll
    for (int am = 0; am < 2; ++am)
#pragma unroll
      for (int bn = 0; bn < 2; ++bn) {
        acc[am][bn] = __builtin_amdgcn_mfma_f32_16x16x32_bf16(ahf[b][am], bhf[b][bn], acc[am][bn], 0, 0, 0);
        if constexpr (BL)
          acc[am][bn] = __builtin_amdgcn_mfma_f32_16x16x32_bf16(ahf[b][am], blf[b][bn], acc[am][bn], 0, 0, 0);
        if constexpr (AL)
          acc[am][bn] = __builtin_amdgcn_mfma_f32_16x16x32_bf16(alf[b][am], bhf[b][bn], acc[am][bn], 0, 0, 0);
      }
  };

  loadk(0, 0);
  if constexpr (KSTEPS > 1) loadk(1, 1);
  if constexpr (KSTEPS > 2) loadk(2, 2);
#pragma unroll
  for (int kk = 0; kk < KSTEPS; ++kk) {
    const int cur = kk & 3;
    if (kk + 3 < KSTEPS) loadk(kk + 3, (cur + 3) & 3);
    domm(cur);
  }

#pragma unroll
  for (int am = 0; am < 2; ++am)
#pragma unroll
    for (int bn = 0; bn < 2; ++bn) {
      int ib = i0 + 16 * am + lk * 4;
      int j = j0 + 16 * bn + lr;
      f32x4 a = acc[am][bn];
      if constexpr (S > 1) {
#pragma unroll
        for (int r = 0; r < 4; ++r) C[((size_t)z * M + ib + r) * N + j] = a[r];
      } else if constexpr (EPI == 0) {
#pragma unroll
        for (int r = 0; r < 4; ++r) C[(size_t)(ib + r) * N + j] = a[r];
      } else if constexpr (EPI == 1) {
#pragma unroll
        for (int r = 0; r < 4; ++r) C[(size_t)(ib + r) * N + j] = rs[ib + r] * a[r];
      } else {
        unsigned long long hp = 0, lp = 0;
#pragma unroll
        for (int r = 0; r < 4; ++r) {
          unsigned short hv, lv;
          split2(rs[ib + r] * a[r], hv, lv);
          hp |= ((unsigned long long)hv) << (16 * r);
          lp |= ((unsigned long long)lv) << (16 * r);
        }
        size_t c = pchunk(j, ib, M >> 5);
        *(unsigned long long*)&Th[c * 8 + (ib & 7)] = hp;
        *(unsigned long long*)&Tl[c * 8 + (ib & 7)] = lp;
      }
    }
}

// ---------------- bf16-split MFMA GEMM, 64x64/wave (split-K partials) ----------------
template <int AL, int BL, int KK, int S>
__global__ __launch_bounds__(256) void gemm64(
    const unsigned short* __restrict__ Ah, const unsigned short* __restrict__ Al,
    const unsigned short* __restrict__ Bh, const unsigned short* __restrict__ Bl,
    int M, int N, float* __restrict__ C) {
  static_assert(KK % 32 == 0, "K");
  constexpr int KSTEPS = KK / 32;
  const int NT = (KK * S) >> 5;
  const int gx = gridDim.x;
  int id = blockIdx.y * gx + blockIdx.x;
  int cpx = (gx * gridDim.y) >> 3;
  int sid = (id & 7) * cpx + (id >> 3);
  const int bx = sid % gx, by = sid / gx;
  const int z = blockIdx.z;
  const int wid = threadIdx.x >> 6, lane = threadIdx.x & 63;
  const int i0 = by * 128 + (wid >> 1) * 64;
  const int j0 = bx * 128 + (wid & 1) * 64;
  const int lr = lane & 15, lk = lane >> 4;
  size_t aoff[4], boff[4];
#pragma unroll
  for (int t = 0; t < 4; ++t) {
    aoff[t] = ((size_t)((i0 >> 4) + t) * NT + z * (KK >> 5)) * 512 + lane * 8;
    boff[t] = ((size_t)((j0 >> 4) + t) * NT + z * (KK >> 5)) * 512 + lane * 8;
  }
  const f32x4 zf = {0.f, 0.f, 0.f, 0.f};
  f32x4 acc[4][4];
#pragma unroll
  for (int a = 0; a < 4; ++a)
#pragma unroll
    for (int b = 0; b < 4; ++b) acc[a][b] = zf;

  bf16x8 ahf[2][4], bhf[2][4], alf[2][4], blf[2][4];
  auto loadk = [&](int kk, int b) {
    size_t o = (size_t)kk * 512;
#pragma unroll
    for (int t = 0; t < 4; ++t) {
      ahf[b][t] = *(const bf16x8*)(Ah + aoff[t] + o);
      bhf[b][t] = *(const bf16x8*)(Bh + boff[t] + o);
      if constexpr (AL) alf[b][t] = *(const bf16x8*)(Al + aoff[t] + o);
      if constexpr (BL) blf[b][t] = *(const bf16x8*)(Bl + boff[t] + o);
    }
  };
  auto domm = [&](int b) {
#pragma unroll
    for (int am = 0; am < 4; ++am)
#pragma unroll
      for (int bn = 0; bn < 4; ++bn) {
        acc[am][bn] = __builtin_amdgcn_mfma_f32_16x16x32_bf16(ahf[b][am], bhf[b][bn], acc[am][bn], 0, 0, 0);
        if constexpr (BL)
          acc[am][bn] = __builtin_amdgcn_mfma_f32_16x16x32_bf16(ahf[b][am], blf[b][bn], acc[am][bn], 0, 0, 0);
        if constexpr (AL)
          acc[am][bn] = __builtin_amdgcn_mfma_f32_16x16x32_bf16(alf[b][am], bhf[b][bn], acc[am][bn], 0, 0, 0);
      }
  };

  loadk(0, 0);
#pragma unroll
  for (int kk = 0; kk < KSTEPS; ++kk) {
    const int cur = kk & 1;
    if (kk + 1 < KSTEPS) loadk(kk + 1, cur ^ 1);
    domm(cur);
  }

#pragma unroll
  for (int am = 0; am < 4; ++am)
#pragma unroll
    for (int bn = 0; bn < 4; ++bn) {
      int ib = i0 + 16 * am + lk * 4;
      int j = j0 + 16 * bn + lr;
      f32x4 a = acc[am][bn];
#pragma unroll
      for (int r = 0; r < 4; ++r) C[((size_t)z * M + ib + r) * N + j] = a[r];
    }
}

// ---------------- launch ----------------

extern "C" void kernel_launch(void* const* d_in, const int* in_sizes, int n_in,
                              void* d_out, int out_size, void* d_ws, size_t ws_size,
                              hipStream_t stream) {
  (void)in_sizes; (void)n_in; (void)out_size; (void)ws_size;
  const float* x  = (const float*)d_in[0];
  const int* ei   = (const int*)d_in[1];
  const int* esrc = ei;
  const int* edst = ei + EE;
  const float* w0 = (const float*)d_in[2];
  const float* b0 = (const float*)d_in[3];
  const float* w1 = (const float*)d_in[4];
  const float* b1 = (const float*)d_in[5];
  const float* w2 = (const float*)d_in[6];
  const float* b2 = (const float*)d_in[7];
  const float* w3 = (const float*)d_in[8];
  const float* b3 = (const float*)d_in[9];
  const float* w4 = (const float*)d_in[10];
  const float* b4 = (const float*)d_in[11];
  const float* p0 = (const float*)d_in[12];
  const float* p1 = (const float*)d_in[13];
  float* out = (float*)d_out;

  char* ws = (char*)d_ws;
  size_t off = 0;
  auto alloc = [&](size_t b) { void* p = ws + off; off += (b + 255) & ~(size_t)255; return p; };

  int* csc_off = (int*)alloc(4 * (NN + 1));
  int* csr_off = (int*)alloc(4 * (NN + 1));
  int* csc_src = (int*)alloc(4 * EE);
  int* csr_dst = (int*)alloc(4 * EE);

  // zeroed region: 4 count arrays + deg2 + rank0 + rank1
  size_t zero_bytes = 4 * NN * 4 + 4 * NP2 + 4 * NN + 4 * NP1;
  int* cnts    = (int*)alloc(zero_bytes);
  int* cnt_dst = cnts;
  int* cnt_src = cnts + NN;
  int* fill_dst = cnts + 2 * NN;
  int* fill_src = cnts + 3 * NN;
  float* deg2 = (float*)(cnts + 4 * NN);
  int* rank0 = (int*)(deg2 + NP2);
  int* rank1 = rank0 + NN;

  int* cntk  = (int*)alloc(4 * NN);   // fully written by rank_place
  int* kept0 = (int*)alloc(4 * NN);
  int* perm0 = (int*)alloc(4 * NP1);
  int* kept1 = (int*)alloc(4 * NP1);
  int* perm1 = (int*)alloc(4 * NP2);
  float* dis0 = (float*)alloc(4 * NN);
  float* dis1 = (float*)alloc(4 * NP1);
  float* dis2 = (float*)alloc(4 * NP2);
  float* pnrm = (float*)alloc(8);
  float* s0   = (float*)alloc(4 * NN);
  float* vals0 = (float*)alloc(4 * NP1);
  float* s1   = (float*)alloc(4 * NP1);
  float* vals1 = (float*)alloc(4 * NP2);
  unsigned long long* keys0 = (unsigned long long*)alloc(8 * NN);
  unsigned long long* keys1 = (unsigned long long*)alloc(8 * NP1);

  const size_t MB = 1024 * 1024;
  // 16MB region: Gh/Hh gathers (0..8MB); later B2 fp32 (0..4MB) + B2t splits (4..8MB)
  char* regB1 = (char*)alloc(16 * MB);
  unsigned short* Gh = (unsigned short*)regB1;
  unsigned short* Hh = (unsigned short*)(regB1 + 4 * MB);
  float* B2   = (float*)regB1;
  unsigned short* B2th = (unsigned short*)(regB1 + 4 * MB);
  unsigned short* B2tl = (unsigned short*)(regB1 + 6 * MB);
  float* pscr = (float*)alloc(16 * MB);  // split-K partials

  unsigned short* B1rm = (unsigned short*)alloc(8 * MB);  // packed bf16 (exact)
  unsigned short* B1t  = (unsigned short*)alloc(8 * MB);  // packed bf16 transpose (exact)
  float* res0 = (float*)alloc(4 * MB);
  float* res1 = (float*)alloc(4 * MB);
  float* yreg = (float*)alloc(4 * MB);
  float* outreg = (float*)alloc(2 * MB);
  float* out2 = outreg, *out3 = outreg;
  char* ytreg = (char*)alloc(4 * MB);
  unsigned short* Y1th = (unsigned short*)ytreg;
  unsigned short* Y1tl = (unsigned short*)(ytreg + 2 * MB);
  unsigned short* Y2th = (unsigned short*)ytreg;
  unsigned short* Y2tl = (unsigned short*)(ytreg + 1 * MB);
  unsigned short* Y3th = (unsigned short*)ytreg;
  unsigned short* Y3tl = (unsigned short*)(ytreg + 1 * MB);
  char* xsreg = (char*)alloc(4 * MB);
  unsigned short* x3h = (unsigned short*)xsreg;
  unsigned short* x3l = (unsigned short*)(xsreg + 2 * MB);
  unsigned short* x4h = (unsigned short*)xsreg;
  unsigned short* x4l = (unsigned short*)(xsreg + 2 * MB);
  unsigned short* xh = (unsigned short*)alloc(1 * MB);
  unsigned short* xl = (unsigned short*)alloc(1 * MB);
  char* xsm = (char*)alloc(2 * MB);
  unsigned short* x1h = (unsigned short*)xsm;
  unsigned short* x1l = (unsigned short*)(xsm + 1 * MB);
  unsigned short* x2h = (unsigned short*)xsm;
  unsigned short* x2l = (unsigned short*)(xsm + 1 * MB);
  unsigned short* Wt0h = (unsigned short*)alloc(256 * 128 * 2);
  unsigned short* Wt0l = (unsigned short*)alloc(256 * 128 * 2);
  unsigned short* Wt1h = (unsigned short*)alloc(512 * 256 * 2);
  unsigned short* Wt1l = (unsigned short*)alloc(512 * 256 * 2);
  unsigned short* Wt2h = (unsigned short*)alloc(512 * 512 * 2);
  unsigned short* Wt2l = (unsigned short*)alloc(512 * 512 * 2);
  unsigned short* Wt3h = (unsigned short*)alloc(256 * 512 * 2);
  unsigned short* Wt3l = (unsigned short*)alloc(256 * 512 * 2);
  unsigned short* Wt4h = (unsigned short*)alloc(128 * 256 * 2);
  unsigned short* Wt4l = (unsigned short*)alloc(128 * 256 * 2);

  hipMemsetAsync(cnts, 0, zero_bytes, stream);

  // graph build
  hist_kernel<<<EE / 256, 256, 0, stream>>>(esrc, edst, cnt_src, cnt_dst, EE);
  scan2<<<2, 1024, 0, stream>>>(cnt_dst, cnt_src, csc_off, csr_off, dis0, NN);
  scatter_kernel<<<EE / 256, 256, 0, stream>>>(esrc, edst, csc_off, csr_off,
                                               fill_dst, fill_src, csc_src, csr_dst, EE);
  pnorm2<<<2, 256, 0, stream>>>(p0, p1, pnrm);

  // operand conversions
  wconv_all<<<288, 256, 0, stream>>>(w0, w1, w2, w3, w4, Wt0h, Wt0l, Wt1h, Wt1l,
                                     Wt2h, Wt2l, Wt3h, Wt3l, Wt4h, Wt4l);
  split_p<<<(NN * 128 / 8) / 256, 256, 0, stream>>>(x, xh, xl, 128);

  // gcn0
  gemm16<1, 1, 1, 128, 1><<<dim3(4, 64), 256, 0, stream>>>(xh, xl, Wt0h, Wt0l,
                                                           NN, 256, dis0, yreg, nullptr, nullptr);
  spmm_gather_v<256><<<NN / 4, 256, 0, stream>>>(yreg, csc_off, csc_src, dis0, b0, res0);

  // pool0
  score_key<<<NN, 256, 0, stream>>>(res0, p0, pnrm + 0, s0, keys0, 256);
  rank_count<<<dim3(NN / 256, NN / 512), 256, 0, stream>>>(keys0, rank0);
  rank_place<<<NN / 256, 256, 0, stream>>>(s0, rank0, NP1, NN, kept0, perm0, vals0, cntk);
  pool_split_p<<<NP1, 64, 0, stream>>>(res0, perm0, vals0, x1h, x1l, 256);

  // augment0: packed B1rm directly, sparse deg, packed transpose
  aug_row_p<<<NP1, 256, 0, stream>>>(csr_off, csr_dst, kept0, perm0, B1rm);
  cnt_edges<<<EE / 256, 256, 0, stream>>>(esrc, edst, kept0, cntk, EE);
  deg_gather<<<NP1 / 4, 256, 0, stream>>>(csc_off, csc_src, cntk, perm0, dis1);
  t_pack<<<dim3(32, 32), 256, 0, stream>>>(B1rm, B1t, NP1);

  // gcn1
  gemm16<2, 1, 1, 256, 1><<<dim3(8, 32), 256, 0, stream>>>(x1h, x1l, Wt1h, Wt1l,
                                                           NP1, 512, dis1, nullptr, Y1th, Y1tl);
  gemm64<0, 1, 512, 4><<<dim3(4, 16, 4), 256, 0, stream>>>(B1t, nullptr, Y1th, Y1tl,
                                                           NP1, 512, pscr);
  ep3<4><<<(NP1 * 512) / 1024, 256, 0, stream>>>(pscr, dis1, b1, res1, NP1, 512);

  // pool1
  score_key<<<NP1, 256, 0, stream>>>(res1, p1, pnrm + 1, s1, keys1, 512);
  rank_count<<<dim3(NP1 / 256, NP1 / 512), 256, 0, stream>>>(keys1, rank1);
  rank_place<<<NP1 / 256, 256, 0, stream>>>(s1, rank1, NP2, NP1, kept1, perm1, vals1, nullptr);
  pool_split_p<<<NP2, 64, 0, stream>>>(res1, perm1, vals1, x2h, x2l, 512);

  // augment1: gathered packed operands -> dense exact GEMM (split-K) -> B2 + colsums
  gather_p<<<(NP2 * NP1 / 8) / 256, 256, 0, stream>>>(B1rm, perm1, Gh, NP1 >> 5);
  gather_p<<<(NP2 * NP1 / 8) / 256, 256, 0, stream>>>(B1t, perm1, Hh, NP1 >> 5);
  gemm64<0, 0, 512, 4><<<dim3(8, 8, 4), 256, 0, stream>>>(Gh, nullptr, Hh, nullptr,
                                                          NP2, NP2, pscr);
  ep_aug_cs<4><<<dim3(NP2 / 256, NP2 / 64), 256, 0, stream>>>(pscr, B2, deg2, NP2);
  dis_from_deg<<<NP2 / 256, 256, 0, stream>>>(deg2, dis2, NP2);
  tsplit_p<<<(NP2 * NP2 / 8) / 256, 256, 0, stream>>>(B2, B2th, B2tl, NP2, NP2);

  // gcn2 (bottleneck)
  gemm16<2, 1, 1, 512, 1><<<dim3(8, 16), 256, 0, stream>>>(x2h, x2l, Wt2h, Wt2l,
                                                           NP2, 512, dis2, nullptr, Y2th, Y2tl);
  gemm16<0, 1, 1, 512, 2><<<dim3(8, 16, 2), 256, 0, stream>>>(B2th, B2tl, Y2th, Y2tl,
                                                              NP2, 512, nullptr, pscr, nullptr, nullptr);
  ep3<2><<<(NP2 * 512) / 1024, 256, 0, stream>>>(pscr, dis2, b2, out2, NP2, 512);

  // up1
  unpool_split_p<<<(NP1 * 512 / 8) / 256, 256, 0, stream>>>(res1, out2, kept1, x3h, x3l, 512);
  gemm16<2, 1, 1, 512, 1><<<dim3(4, 32), 256, 0, stream>>>(x3h, x3l, Wt3h, Wt3l,
                                                           NP1, 256, dis1, nullptr, Y3th, Y3tl);
  gemm64<0, 1, 256, 8><<<dim3(2, 16, 8), 256, 0, stream>>>(B1t, nullptr, Y3th, Y3tl,
                                                           NP1, 256, pscr);
  ep3<8><<<(NP1 * 256) / 1024, 256, 0, stream>>>(pscr, dis1, b3, out3, NP1, 256);

  // up0
  unpool_split_p<<<(NN * 256 / 8) / 256, 256, 0, stream>>>(res0, out3, kept0, x4h, x4l, 256);
  gemm16<1, 1, 1, 256, 1><<<dim3(2, 64), 256, 0, stream>>>(x4h, x4l, Wt4h, Wt4l,
                                                           NN, 128, dis0, yreg, nullptr, nullptr);
  spmm_gather_v<128><<<NN / 4, 256, 0, stream>>>(yreg, csc_off, csc_src, dis0, b4, out);
}

// Round 10
// 339.835 us; speedup vs baseline: 1.2124x; 1.0121x over previous
//
#include <hip/hip_runtime.h>

#define NN 4096
#define EE 131072
#define NP1 2048
#define NP2 1024

typedef __attribute__((ext_vector_type(8))) __bf16 bf16x8;
typedef __attribute__((ext_vector_type(4))) float f32x4;
typedef __attribute__((ext_vector_type(8))) unsigned short ushort8;

static __device__ inline unsigned short bfbits(__bf16 b) {
  union { __bf16 x; unsigned short u; } c; c.x = b; return c.u;
}
static __device__ inline void split2(float v, unsigned short& h, unsigned short& l) {
  __bf16 hb = (__bf16)v;
  float hf = (float)hb;
  __bf16 lb = (__bf16)(v - hf);
  h = bfbits(hb); l = bfbits(lb);
}

// Packed fragment layout for [R rows][K k] bf16 (R%16==0, K%32==0):
// 16x32 tile (rt,kt); chunk-in-tile = ((k>>3)&3)*16 + (r&15) == MFMA lane id.
static __device__ inline size_t pchunk(int r, int k, int NT) {
  return ((size_t)(r >> 4) * NT + (k >> 5)) * 64 + (((k >> 3) & 3) << 4) + (r & 15);
}

// ---------------- graph build ----------------

__global__ void hist_kernel(const int* __restrict__ src, const int* __restrict__ dst,
                            int* __restrict__ cnt_src, int* __restrict__ cnt_dst, int E) {
  int e = blockIdx.x * blockDim.x + threadIdx.x;
  if (e < E) {
    atomicAdd(&cnt_src[src[e]], 1);
    atomicAdd(&cnt_dst[dst[e]], 1);
  }
}

// both exclusive scans in one launch; block 0 also emits dis0
__global__ __launch_bounds__(1024) void scan2(const int* __restrict__ cnt_dst,
                                              const int* __restrict__ cnt_src,
                                              int* __restrict__ csc_off, int* __restrict__ csr_off,
                                              float* __restrict__ dis0, int n) {
  __shared__ int tmp[4096];
  const int* in = blockIdx.x ? cnt_src : cnt_dst;
  int* out = blockIdx.x ? csr_off : csc_off;
  int tid = threadIdx.x;
  for (int i = tid; i < n; i += 1024) {
    int v = in[i];
    tmp[i] = v;
    if (blockIdx.x == 0) dis0[i] = rsqrtf((float)v + 1.0f);
  }
  __syncthreads();
  for (int off = 1; off < n; off <<= 1) {
    int v[4];
    int c = 0;
    for (int i = tid; i < n; i += 1024) { v[c++] = (i >= off) ? tmp[i - off] : 0; }
    __syncthreads();
    c = 0;
    for (int i = tid; i < n; i += 1024) { tmp[i] += v[c++]; }
    __syncthreads();
  }
  for (int i = tid; i < n; i += 1024) out[i + 1] = tmp[i];
  if (tid == 0) out[0] = 0;
}

__global__ void scatter_kernel(const int* __restrict__ src, const int* __restrict__ dst,
                               const int* __restrict__ csc_off, const int* __restrict__ csr_off,
                               int* __restrict__ fill_dst, int* __restrict__ fill_src,
                               int* __restrict__ csc_src, int* __restrict__ csr_dst, int E) {
  int e = blockIdx.x * blockDim.x + threadIdx.x;
  if (e < E) {
    int s = src[e], d = dst[e];
    int p = atomicAdd(&fill_dst[d], 1);
    csc_src[csc_off[d] + p] = s;
    int q = atomicAdd(&fill_src[s], 1);
    csr_dst[csr_off[s] + q] = d;
  }
}

// both p-norms in one launch
__global__ void pnorm2(const float* __restrict__ p0, const float* __restrict__ p1,
                       float* __restrict__ outv) {
  const float* p = blockIdx.x ? p1 : p0;
  int C = blockIdx.x ? 512 : 256;
  int tid = threadIdx.x;
  float acc = 0.f;
  for (int j = tid; j < C; j += 256) { float v = p[j]; acc += v * v; }
  for (int o = 32; o > 0; o >>= 1) acc += __shfl_down(acc, o);
  __shared__ float red[4];
  if ((tid & 63) == 0) red[tid >> 6] = acc;
  __syncthreads();
  if (tid == 0) outv[blockIdx.x] = sqrtf(red[0] + red[1] + red[2] + red[3]);
}

// ---------------- scoring / topk ----------------

__global__ void score_key(const float* __restrict__ X, const float* __restrict__ p,
                          const float* __restrict__ pn, float* __restrict__ s,
                          unsigned long long* __restrict__ keys, int C) {
  int i = blockIdx.x;
  int tid = threadIdx.x;
  float acc = 0.f;
  for (int j = tid; j < C; j += 256) acc += X[(size_t)i * C + j] * p[j];
  for (int o = 32; o > 0; o >>= 1) acc += __shfl_down(acc, o);
  __shared__ float red[4];
  if ((tid & 63) == 0) red[tid >> 6] = acc;
  __syncthreads();
  if (tid == 0) {
    float sv = tanhf((red[0] + red[1] + red[2] + red[3]) / pn[0]);
    s[i] = sv;
    unsigned u = __float_as_uint(sv);
    unsigned m = (u & 0x80000000u) ? ~u : (u | 0x80000000u);
    keys[i] = (((unsigned long long)(~m)) << 32) | (unsigned)i;  // desc value, asc index
  }
}

// partial rank: block (bx,by) counts keys[by*512..+512) against candidates [bx*256..+256)
__global__ __launch_bounds__(256) void rank_count(const unsigned long long* __restrict__ keys,
                                                  int* __restrict__ rank) {
  __shared__ unsigned long long kk[512];
  int tid = threadIdx.x;
  int cand = blockIdx.x * 256 + tid;
  int base = blockIdx.y * 512;
  kk[tid] = keys[base + tid];
  kk[tid + 256] = keys[base + tid + 256];
  __syncthreads();
  unsigned long long kc = keys[cand];
  int c = 0;
#pragma unroll 8
  for (int t = 0; t < 512; ++t) c += (kk[t] < kc) ? 1 : 0;
  atomicAdd(&rank[cand], c);
}

// place by rank; optionally emit cntk (1 if kept) for the sparse-deg path
__global__ void rank_place(const float* __restrict__ s, const int* __restrict__ rank, int k, int n,
                           int* __restrict__ kept, int* __restrict__ perm, float* __restrict__ vals,
                           int* __restrict__ cntk) {
  int i = blockIdx.x * blockDim.x + threadIdx.x;
  if (i < n) {
    int r = rank[i];
    int isk = (r < k) ? 1 : 0;
    if (isk) { perm[r] = i; vals[r] = s[i]; kept[i] = r; }
    else kept[i] = -1;
    if (cntk) cntk[i] = isk;
  }
}

// pooled row gather + gate + dis1 pre-scale -> fp32 row-major
__global__ void pool_gather_s(const float* __restrict__ X, const int* __restrict__ perm,
                              const float* __restrict__ vals, const float* __restrict__ dis,
                              float* __restrict__ out, int C) {
  int a = blockIdx.x;
  int r = perm[a];
  float v = vals[a] * dis[a];
  for (int j = threadIdx.x; j < C; j += blockDim.x)
    out[(size_t)a * C + j] = X[(size_t)r * C + j] * v;
}

// pooled row gather + gate + bf16 split into PACKED layout (unscaled; rs in gemm epilogue)
__global__ void pool_split_p(const float* __restrict__ X, const int* __restrict__ perm,
                             const float* __restrict__ vals, unsigned short* __restrict__ h,
                             unsigned short* __restrict__ l, int C) {
  int a = blockIdx.x;
  int r = perm[a];
  float v = vals[a];
  int NT = C >> 5;
  for (int j0 = threadIdx.x * 8; j0 < C; j0 += 64 * 8) {
    ushort8 hv, lv;
#pragma unroll
    for (int e = 0; e < 8; ++e) {
      unsigned short he, le;
      split2(X[(size_t)r * C + j0 + e] * v, he, le);
      hv[e] = he; lv[e] = le;
    }
    size_t c = pchunk(a, j0, NT);
    *(ushort8*)&h[c * 8] = hv;
    *(ushort8*)&l[c * 8] = lv;
  }
}

// ---------------- augment 0: sparse 2-path rows, packed bf16 output ----------------

__global__ __launch_bounds__(256) void aug_row_p(const int* __restrict__ csr_off,
                                                 const int* __restrict__ csr_dst,
                                                 const int* __restrict__ kept,
                                                 const int* __restrict__ perm,
                                                 unsigned short* __restrict__ rm) {
  __shared__ float acc[NP1];
  int ki = blockIdx.x;
  int r = perm[ki];
  for (int t = threadIdx.x; t < NP1; t += 256) acc[t] = 0.f;
  __syncthreads();
  int s = csr_off[r], e = csr_off[r + 1];
  int nm = e - s;
  int wave = threadIdx.x >> 6, lane = threadIdx.x & 63;
  for (int m = wave; m <= nm; m += 4) {
    int k = (m < nm) ? csr_dst[s + m] : r;
    int s2 = csr_off[k], e2 = csr_off[k + 1];
    int n2 = e2 - s2;
    for (int t = lane; t <= n2; t += 64) {
      int j = (t < n2) ? csr_dst[s2 + t] : k;
      int kj = kept[j];
      if (kj >= 0) atomicAdd(&acc[kj], 1.0f);
    }
  }
  __syncthreads();
  if (threadIdx.x == 0) acc[ki] += 1.0f;  // +I on pooled graph
  __syncthreads();
  int tid = threadIdx.x;
  ushort8 hv;
#pragma unroll
  for (int e8 = 0; e8 < 8; ++e8) hv[e8] = bfbits((__bf16)acc[tid * 8 + e8]);
  size_t dst = (((size_t)(ki >> 4)) * 64 + (tid >> 2)) * 64 + (size_t)(tid & 3) * 16 + (ki & 15);
  *(ushort8*)&rm[dst * 8] = hv;
}

// cntk[d] += [kept src] per edge occurrence (init by rank_place)
__global__ void cnt_edges(const int* __restrict__ src, const int* __restrict__ dst,
                          const int* __restrict__ kept, int* __restrict__ cntk, int E) {
  int e = blockIdx.x * blockDim.x + threadIdx.x;
  if (e < E && kept[src[e]] >= 0) atomicAdd(&cntk[dst[e]], 1);
}

// dis1[c] = rsqrt(1 + cntk[perm[c]] + sum_{s in in(perm[c])} cntk[s])
__global__ __launch_bounds__(256) void deg_gather(const int* __restrict__ csc_off,
                                                  const int* __restrict__ csc_src,
                                                  const int* __restrict__ cntk,
                                                  const int* __restrict__ perm,
                                                  float* __restrict__ dis) {
  int wid = threadIdx.x >> 6, lane = threadIdx.x & 63;
  int c = blockIdx.x * 4 + wid;
  int r = perm[c];
  int s = csc_off[r], e = csc_off[r + 1];
  int sum = 0;
  for (int t = s + lane; t < e; t += 64) sum += cntk[csc_src[t]];
  for (int o = 32; o > 0; o >>= 1) sum += __shfl_down(sum, o);
  if (lane == 0) dis[c] = rsqrtf((float)(sum + cntk[r] + 1));
}

// packed bf16 [n][n] -> packed bf16 transpose (exact)
__global__ __launch_bounds__(256) void t_pack(const unsigned short* __restrict__ in,
                                              unsigned short* __restrict__ outp, int n) {
  __shared__ unsigned short t[64][72];
  int r0 = blockIdx.y * 64, c0 = blockIdx.x * 64;
  int NT = n >> 5;
  for (int q = threadIdx.x; q < 512; q += 256) {
    int lt = q >> 6, l = q & 63;
    int rt = lt >> 1, kt2 = lt & 1;
    int r = rt * 16 + (l & 15), k = kt2 * 32 + (l >> 4) * 8;
    ushort8 v = *(const ushort8*)&in[pchunk(r0 + r, c0 + k, NT) * 8];
    *(ushort8*)&t[r][k] = v;
  }
  __syncthreads();
  for (int q = threadIdx.x; q < 512; q += 256) {
    int lt = q >> 6, l = q & 63;
    int jt = lt >> 1, kt2 = lt & 1;
    int j = jt * 16 + (l & 15), k = kt2 * 32 + (l >> 4) * 8;
    ushort8 v;
#pragma unroll
    for (int e = 0; e < 8; ++e) v[e] = t[k + e][j];
    *(ushort8*)&outp[pchunk(c0 + j, r0 + k, NT) * 8] = v;
  }
}

__global__ void dis_from_deg(const float* __restrict__ deg, float* __restrict__ dis, int n) {
  int i = blockIdx.x * blockDim.x + threadIdx.x;
  if (i < n) dis[i] = rsqrtf(deg[i]);
}

// ---------------- conversions ----------------

// fp32 row-major [R][K] -> packed bf16 hi/lo
__global__ void split_p(const float* __restrict__ in, unsigned short* __restrict__ h,
                        unsigned short* __restrict__ l, int K) {
  int c = blockIdx.x * blockDim.x + threadIdx.x;
  int lane = c & 63, tile = c >> 6;
  int NT = K >> 5;
  int kt = tile % NT, rt = tile / NT;
  int r = rt * 16 + (lane & 15);
  int k = kt * 32 + (lane >> 4) * 8;
  const float* p = in + (size_t)r * K + k;
  ushort8 hv, lv;
#pragma unroll
  for (int e = 0; e < 8; ++e) {
    unsigned short he, le;
    split2(p[e], he, le);
    hv[e] = he; lv[e] = le;
  }
  *(ushort8*)&h[(size_t)c * 8] = hv;
  *(ushort8*)&l[(size_t)c * 8] = lv;
}

static __device__ inline void tsplit_body(const float* in, unsigned short* oh, unsigned short* ol,
                                          int R, int C, int c) {
  int lane = c & 63, tile = c >> 6;
  int NT = R >> 5;
  int kt = tile % NT, jt = tile / NT;
  int j = jt * 16 + (lane & 15);
  int k = kt * 32 + (lane >> 4) * 8;
  ushort8 hv, lv;
#pragma unroll
  for (int e = 0; e < 8; ++e) {
    unsigned short he, le;
    split2(in[(size_t)(k + e) * C + j], he, le);
    hv[e] = he; lv[e] = le;
  }
  *(ushort8*)&oh[(size_t)c * 8] = hv;
  *(ushort8*)&ol[(size_t)c * 8] = lv;
}

__global__ void tsplit_p(const float* __restrict__ in, unsigned short* __restrict__ oh,
                         unsigned short* __restrict__ ol, int R, int C) {
  int c = blockIdx.x * blockDim.x + threadIdx.x;
  tsplit_body(in, oh, ol, R, C, c);
}

// all five weight transpose-splits in one launch
__global__ void wconv_all(const float* w0, const float* w1, const float* w2,
                          const float* w3, const float* w4,
                          unsigned short* o0h, unsigned short* o0l,
                          unsigned short* o1h, unsigned short* o1l,
                          unsigned short* o2h, unsigned short* o2l,
                          unsigned short* o3h, unsigned short* o3l,
                          unsigned short* o4h, unsigned short* o4l) {
  int g = blockIdx.x * blockDim.x + threadIdx.x;
  if (g < 4096)        tsplit_body(w0, o0h, o0l, 128, 256, g);
  else if (g < 20480)  tsplit_body(w1, o1h, o1l, 256, 512, g - 4096);
  else if (g < 53248)  tsplit_body(w2, o2h, o2l, 512, 512, g - 20480);
  else if (g < 69632)  tsplit_body(w3, o3h, o3l, 512, 256, g - 53248);
  else                 tsplit_body(w4, o4h, o4l, 256, 128, g - 69632);
}

// two packed row-gathers in one launch (blockIdx.y selects)
__global__ void gather2_p(const unsigned short* __restrict__ in0, const unsigned short* __restrict__ in1,
                          const int* __restrict__ perm,
                          unsigned short* __restrict__ out0, unsigned short* __restrict__ out1, int NT) {
  const unsigned short* in = blockIdx.y ? in1 : in0;
  unsigned short* outp = blockIdx.y ? out1 : out0;
  int c = blockIdx.x * blockDim.x + threadIdx.x;
  int lane = c & 63, tile = c >> 6;
  int kt = tile % NT, at = tile / NT;
  int a = at * 16 + (lane & 15);
  int sub = lane >> 4;
  int p = perm[a];
  size_t sc = ((size_t)(p >> 4) * NT + kt) * 64 + sub * 16 + (p & 15);
  *(ushort8*)&outp[(size_t)c * 8] = *(const ushort8*)&in[sc * 8];
}

__global__ void unpool_split_p(const float* __restrict__ res, const float* __restrict__ up,
                               const int* __restrict__ kept, unsigned short* __restrict__ h,
                               unsigned short* __restrict__ l, int C) {
  int c = blockIdx.x * blockDim.x + threadIdx.x;
  int lane = c & 63, tile = c >> 6;
  int NT = C >> 5;
  int kt = tile % NT, rt = tile / NT;
  int r = rt * 16 + (lane & 15);
  int j0 = kt * 32 + (lane >> 4) * 8;
  int kv = kept[r];
  ushort8 hv, lv;
#pragma unroll
  for (int e = 0; e < 8; ++e) {
    float v = res[(size_t)r * C + j0 + e];
    if (kv >= 0) v += up[(size_t)kv * C + j0 + e];
    unsigned short he, le;
    split2(v, he, le);
    hv[e] = he; lv[e] = le;
  }
  *(ushort8*)&h[(size_t)c * 8] = hv;
  *(ushort8*)&l[(size_t)c * 8] = lv;
}

// ---------------- sparse aggregation ----------------

// A-first spmm: G[c][j] = dis[c] * ( dis[c]*x[c][j] + sum_src dis[src]*x[src][j] )
template <int C>
__global__ __launch_bounds__(256) void spmm_pre(const float* __restrict__ X,
                                                const int* __restrict__ off,
                                                const int* __restrict__ srcs,
                                                const float* __restrict__ dis,
                                                float* __restrict__ out) {
  constexpr int VEC = C / 64;
  int w = threadIdx.x >> 6, lane = threadIdx.x & 63;
  int c = blockIdx.x * 4 + w;
  int j = lane * VEC;
  float dc = dis[c];
  float acc[VEC];
  const float* p = X + (size_t)c * C + j;
#pragma unroll
  for (int u = 0; u < VEC; ++u) acc[u] = dc * p[u];
  int s = off[c], e = off[c + 1];
  for (int t = s; t < e; ++t) {
    int sr = srcs[t];
    float ds = dis[sr];
    const float* q = X + (size_t)sr * C + j;
#pragma unroll
    for (int u = 0; u < VEC; ++u) acc[u] += ds * q[u];
  }
  float* o = out + (size_t)c * C + j;
#pragma unroll
  for (int u = 0; u < VEC; ++u) o[u] = dc * acc[u];
}

// X-first spmm (gcn4): out = relu(dis[c]*(sum of pre-scaled rows) + bias)
template <int C>
__global__ __launch_bounds__(256) void spmm_gather_v(const float* __restrict__ Y,
                                                     const int* __restrict__ off,
                                                     const int* __restrict__ srcs,
                                                     const float* __restrict__ dis,
                                                     const float* __restrict__ bias,
                                                     float* __restrict__ out) {
  constexpr int VEC = C / 64;
  int w = threadIdx.x >> 6, lane = threadIdx.x & 63;
  int c = blockIdx.x * 4 + w;
  int j = lane * VEC;
  float acc[VEC];
  const float* p = Y + (size_t)c * C + j;
#pragma unroll
  for (int u = 0; u < VEC; ++u) acc[u] = p[u];
  int s = off[c], e = off[c + 1];
  for (int t = s; t < e; ++t) {
    const float* q = Y + (size_t)srcs[t] * C + j;
#pragma unroll
    for (int u = 0; u < VEC; ++u) acc[u] += q[u];
  }
  float d = dis[c];
  float* o = out + (size_t)c * C + j;
#pragma unroll
  for (int u = 0; u < VEC; ++u) o[u] = fmaxf(d * acc[u] + bias[j + u], 0.0f);
}

// ---------------- split-K combines ----------------

template <int S>
__global__ void ep3(const float* __restrict__ p, const float* __restrict__ rs,
                    const float* __restrict__ bias, float* __restrict__ outp, int M, int N) {
  int idx = blockIdx.x * blockDim.x + threadIdx.x;
  int j4 = (idx * 4) % N, i = (idx * 4) / N;
  float4 a = {0.f, 0.f, 0.f, 0.f};
#pragma unroll
  for (int s = 0; s < S; ++s) {
    float4 b = *(const float4*)(p + ((size_t)s * M + i) * N + j4);
    a.x += b.x; a.y += b.y; a.z += b.z; a.w += b.w;
  }
  float r = rs[i];
  float4 o;
  o.x = fmaxf(r * a.x + bias[j4 + 0], 0.f);
  o.y = fmaxf(r * a.y + bias[j4 + 1], 0.f);
  o.z = fmaxf(r * a.z + bias[j4 + 2], 0.f);
  o.w = fmaxf(r * a.w + bias[j4 + 3], 0.f);
  *(float4*)(outp + (size_t)i * N + j4) = o;
}

// combine S partials -> packed bf16 hi/lo row-major (for Z = B1^T Xs)
template <int S>
__global__ void ep_zsplit(const float* __restrict__ p, unsigned short* __restrict__ h,
                          unsigned short* __restrict__ l, int M, int N) {
  int t = blockIdx.x * blockDim.x + threadIdx.x;  // chunk id over M*N/8
  int tile = t >> 6, w = t & 63;
  int NT = N >> 5;
  int rt = tile / NT, kt = tile % NT;
  int r = rt * 16 + (w & 15);
  int k = kt * 32 + (w >> 4) * 8;
  const float* p0 = p + (size_t)r * N + k;
  ushort8 hv, lv;
#pragma unroll
  for (int e = 0; e < 8; ++e) {
    float v = p0[e];
#pragma unroll
    for (int s = 1; s < S; ++s) v += p0[(size_t)s * M * N + e];
    unsigned short he, le;
    split2(v, he, le);
    hv[e] = he; lv[e] = le;
  }
  *(ushort8*)&h[(size_t)t * 8] = hv;
  *(ushort8*)&l[(size_t)t * 8] = lv;
}

// combine S partials (+I) -> B2 fp32, and accumulate column sums into deg
template <int S>
__global__ void ep_aug_cs(const float* __restrict__ p, float* __restrict__ B,
                          float* __restrict__ deg, int n) {
  int c = blockIdx.x * 256 + threadIdx.x;
  int r0 = blockIdx.y * 64;
  float cs = 0.f;
  for (int r = r0; r < r0 + 64; ++r) {
    float v = 0.f;
#pragma unroll
    for (int s = 0; s < S; ++s) v += p[((size_t)s * n + r) * n + c];
    if (r == c) v += 1.0f;
    B[(size_t)r * n + c] = v;
    cs += v;
  }
  atomicAdd(&deg[c], cs);
}

// ---------------- bf16-split MFMA GEMM, 32x32/wave ----------------
// S>1: partial to C + z*M*N. S==1 EPI: 0 plain; 1 rowscale; 2 rowscale+packed-T-split;
// 3 rowscale+bias+relu; 4 bias+relu
template <int EPI, int AL, int BL, int KK, int S>
__global__ __launch_bounds__(256) void gemm16(
    const unsigned short* __restrict__ Ah, const unsigned short* __restrict__ Al,
    const unsigned short* __restrict__ Bh, const unsigned short* __restrict__ Bl,
    int M, int N, const float* __restrict__ rs, const float* __restrict__ bias,
    float* __restrict__ C, unsigned short* __restrict__ Th, unsigned short* __restrict__ Tl) {
  static_assert(KK % 32 == 0, "K");
  constexpr int KSTEPS = KK / 32;
  const int NT = (KK * S) >> 5;
  const int gx = gridDim.x;
  int id = blockIdx.y * gx + blockIdx.x;
  int cpx = (gx * gridDim.y) >> 3;
  int sid = (id & 7) * cpx + (id >> 3);
  const int bx = sid % gx, by = sid / gx;
  const int z = (S > 1) ? blockIdx.z : 0;
  const int wid = threadIdx.x >> 6, lane = threadIdx.x & 63;
  const int i0 = by * 64 + (wid >> 1) * 32;
  const int j0 = bx * 64 + (wid & 1) * 32;
  const int lr = lane & 15, lk = lane >> 4;
  size_t aoff[2], boff[2];
#pragma unroll
  for (int t = 0; t < 2; ++t) {
    aoff[t] = ((size_t)((i0 >> 4) + t) * NT + z * (KK >> 5)) * 512 + lane * 8;
    boff[t] = ((size_t)((j0 >> 4) + t) * NT + z * (KK >> 5)) * 512 + lane * 8;
  }
  const f32x4 zf = {0.f, 0.f, 0.f, 0.f};
  f32x4 acc[2][2];
  acc[0][0] = zf; acc[0][1] = zf; acc[1][0] = zf; acc[1][1] = zf;

  bf16x8 ahf[4][2], bhf[4][2], alf[4][2], blf[4][2];
  auto loadk = [&](int kk, int b) {
    size_t o = (size_t)kk * 512;
    ahf[b][0] = *(const bf16x8*)(Ah + aoff[0] + o);
    ahf[b][1] = *(const bf16x8*)(Ah + aoff[1] + o);
    bhf[b][0] = *(const bf16x8*)(Bh + boff[0] + o);
    bhf[b][1] = *(const bf16x8*)(Bh + boff[1] + o);
    if constexpr (AL) {
      alf[b][0] = *(const bf16x8*)(Al + aoff[0] + o);
      alf[b][1] = *(const bf16x8*)(Al + aoff[1] + o);
    }
    if constexpr (BL) {
      blf[b][0] = *(const bf16x8*)(Bl + boff[0] + o);
      blf[b][1] = *(const bf16x8*)(Bl + boff[1] + o);
    }
  };
  auto domm = [&](int b) {
#pragma unroll
    for (int am = 0; am < 2; ++am)
#pragma unroll
      for (int bn = 0; bn < 2; ++bn) {
        acc[am][bn] = __builtin_amdgcn_mfma_f32_16x16x32_bf16(ahf[b][am], bhf[b][bn], acc[am][bn], 0, 0, 0);
        if constexpr (BL)
          acc[am][bn] = __builtin_amdgcn_mfma_f32_16x16x32_bf16(ahf[b][am], blf[b][bn], acc[am][bn], 0, 0, 0);
        if constexpr (AL)
          acc[am][bn] = __builtin_amdgcn_mfma_f32_16x16x32_bf16(alf[b][am], bhf[b][bn], acc[am][bn], 0, 0, 0);
      }
  };

  loadk(0, 0);
  if constexpr (KSTEPS > 1) loadk(1, 1);
  if constexpr (KSTEPS > 2) loadk(2, 2);
#pragma unroll
  for (int kk = 0; kk < KSTEPS; ++kk) {
    const int cur = kk & 3;
    if (kk + 3 < KSTEPS) loadk(kk + 3, (cur + 3) & 3);
    domm(cur);
  }

#pragma unroll
  for (int am = 0; am < 2; ++am)
#pragma unroll
    for (int bn = 0; bn < 2; ++bn) {
      int ib = i0 + 16 * am + lk * 4;
      int j = j0 + 16 * bn + lr;
      f32x4 a = acc[am][bn];
      if constexpr (S > 1) {
#pragma unroll
        for (int r = 0; r < 4; ++r) C[((size_t)z * M + ib + r) * N + j] = a[r];
      } else if constexpr (EPI == 0) {
#pragma unroll
        for (int r = 0; r < 4; ++r) C[(size_t)(ib + r) * N + j] = a[r];
      } else if constexpr (EPI == 1) {
#pragma unroll
        for (int r = 0; r < 4; ++r) C[(size_t)(ib + r) * N + j] = rs[ib + r] * a[r];
      } else if constexpr (EPI == 2) {
        unsigned long long hp = 0, lp = 0;
#pragma unroll
        for (int r = 0; r < 4; ++r) {
          unsigned short hv, lv;
          split2(rs[ib + r] * a[r], hv, lv);
          hp |= ((unsigned long long)hv) << (16 * r);
          lp |= ((unsigned long long)lv) << (16 * r);
        }
        size_t c = pchunk(j, ib, M >> 5);
        *(unsigned long long*)&Th[c * 8 + (ib & 7)] = hp;
        *(unsigned long long*)&Tl[c * 8 + (ib & 7)] = lp;
      } else if constexpr (EPI == 3) {
#pragma unroll
        for (int r = 0; r < 4; ++r)
          C[(size_t)(ib + r) * N + j] = fmaxf(rs[ib + r] * a[r] + bias[j], 0.0f);
      } else {
#pragma unroll
        for (int r = 0; r < 4; ++r)
          C[(size_t)(ib + r) * N + j] = fmaxf(a[r] + bias[j], 0.0f);
      }
    }
}

// ---------------- bf16-split MFMA GEMM, 64x64/wave (split-K partials) ----------------
template <int AL, int BL, int KK, int S>
__global__ __launch_bounds__(256) void gemm64(
    const unsigned short* __restrict__ Ah, const unsigned short* __restrict__ Al,
    const unsigned short* __restrict__ Bh, const unsigned short* __restrict__ Bl,
    int M, int N, float* __restrict__ C) {
  static_assert(KK % 32 == 0, "K");
  constexpr int KSTEPS = KK / 32;
  const int NT = (KK * S) >> 5;
  const int gx = gridDim.x;
  int id = blockIdx.y * gx + blockIdx.x;
  int cpx = (gx * gridDim.y) >> 3;
  int sid = (id & 7) * cpx + (id >> 3);
  const int bx = sid % gx, by = sid / gx;
  const int z = blockIdx.z;
  const int wid = threadIdx.x >> 6, lane = threadIdx.x & 63;
  const int i0 = by * 128 + (wid >> 1) * 64;
  const int j0 = bx * 128 + (wid & 1) * 64;
  const int lr = lane & 15, lk = lane >> 4;
  size_t aoff[4], boff[4];
#pragma unroll
  for (int t = 0; t < 4; ++t) {
    aoff[t] = ((size_t)((i0 >> 4) + t) * NT + z * (KK >> 5)) * 512 + lane * 8;
    boff[t] = ((size_t)((j0 >> 4) + t) * NT + z * (KK >> 5)) * 512 + lane * 8;
  }
  const f32x4 zf = {0.f, 0.f, 0.f, 0.f};
  f32x4 acc[4][4];
#pragma unroll
  for (int a = 0; a < 4; ++a)
#pragma unroll
    for (int b = 0; b < 4; ++b) acc[a][b] = zf;

  bf16x8 ahf[2][4], bhf[2][4], alf[2][4], blf[2][4];
  auto loadk = [&](int kk, int b) {
    size_t o = (size_t)kk * 512;
#pragma unroll
    for (int t = 0; t < 4; ++t) {
      ahf[b][t] = *(const bf16x8*)(Ah + aoff[t] + o);
      bhf[b][t] = *(const bf16x8*)(Bh + boff[t] + o);
      if constexpr (AL) alf[b][t] = *(const bf16x8*)(Al + aoff[t] + o);
      if constexpr (BL) blf[b][t] = *(const bf16x8*)(Bl + boff[t] + o);
    }
  };
  auto domm = [&](int b) {
#pragma unroll
    for (int am = 0; am < 4; ++am)
#pragma unroll
      for (int bn = 0; bn < 4; ++bn) {
        acc[am][bn] = __builtin_amdgcn_mfma_f32_16x16x32_bf16(ahf[b][am], bhf[b][bn], acc[am][bn], 0, 0, 0);
        if constexpr (BL)
          acc[am][bn] = __builtin_amdgcn_mfma_f32_16x16x32_bf16(ahf[b][am], blf[b][bn], acc[am][bn], 0, 0, 0);
        if constexpr (AL)
          acc[am][bn] = __builtin_amdgcn_mfma_f32_16x16x32_bf16(alf[b][am], bhf[b][bn], acc[am][bn], 0, 0, 0);
      }
  };

  loadk(0, 0);
#pragma unroll
  for (int kk = 0; kk < KSTEPS; ++kk) {
    const int cur = kk & 1;
    if (kk + 1 < KSTEPS) loadk(kk + 1, cur ^ 1);
    domm(cur);
  }

#pragma unroll
  for (int am = 0; am < 4; ++am)
#pragma unroll
    for (int bn = 0; bn < 4; ++bn) {
      int ib = i0 + 16 * am + lk * 4;
      int j = j0 + 16 * bn + lr;
      f32x4 a = acc[am][bn];
#pragma unroll
      for (int r = 0; r < 4; ++r) C[((size_t)z * M + ib + r) * N + j] = a[r];
    }
}

// ---------------- launch ----------------

extern "C" void kernel_launch(void* const* d_in, const int* in_sizes, int n_in,
                              void* d_out, int out_size, void* d_ws, size_t ws_size,
                              hipStream_t stream) {
  (void)in_sizes; (void)n_in; (void)out_size; (void)ws_size;
  const float* x  = (const float*)d_in[0];
  const int* ei   = (const int*)d_in[1];
  const int* esrc = ei;
  const int* edst = ei + EE;
  const float* w0 = (const float*)d_in[2];
  const float* b0 = (const float*)d_in[3];
  const float* w1 = (const float*)d_in[4];
  const float* b1 = (const float*)d_in[5];
  const float* w2 = (const float*)d_in[6];
  const float* b2 = (const float*)d_in[7];
  const float* w3 = (const float*)d_in[8];
  const float* b3 = (const float*)d_in[9];
  const float* w4 = (const float*)d_in[10];
  const float* b4 = (const float*)d_in[11];
  const float* p0 = (const float*)d_in[12];
  const float* p1 = (const float*)d_in[13];
  float* out = (float*)d_out;

  char* ws = (char*)d_ws;
  size_t off = 0;
  auto alloc = [&](size_t b) { void* p = ws + off; off += (b + 255) & ~(size_t)255; return p; };

  int* csc_off = (int*)alloc(4 * (NN + 1));
  int* csr_off = (int*)alloc(4 * (NN + 1));
  int* csc_src = (int*)alloc(4 * EE);
  int* csr_dst = (int*)alloc(4 * EE);

  // zeroed region: 4 count arrays + deg2 + rank0 + rank1
  size_t zero_bytes = 4 * NN * 4 + 4 * NP2 + 4 * NN + 4 * NP1;
  int* cnts    = (int*)alloc(zero_bytes);
  int* cnt_dst = cnts;
  int* cnt_src = cnts + NN;
  int* fill_dst = cnts + 2 * NN;
  int* fill_src = cnts + 3 * NN;
  float* deg2 = (float*)(cnts + 4 * NN);
  int* rank0 = (int*)(deg2 + NP2);
  int* rank1 = rank0 + NN;

  int* cntk  = (int*)alloc(4 * NN);
  int* kept0 = (int*)alloc(4 * NN);
  int* perm0 = (int*)alloc(4 * NP1);
  int* kept1 = (int*)alloc(4 * NP1);
  int* perm1 = (int*)alloc(4 * NP2);
  float* dis0 = (float*)alloc(4 * NN);
  float* dis1 = (float*)alloc(4 * NP1);
  float* dis2 = (float*)alloc(4 * NP2);
  float* pnrm = (float*)alloc(8);
  float* s0   = (float*)alloc(4 * NN);
  float* vals0 = (float*)alloc(4 * NP1);
  float* s1   = (float*)alloc(4 * NP1);
  float* vals1 = (float*)alloc(4 * NP2);
  unsigned long long* keys0 = (unsigned long long*)alloc(8 * NN);
  unsigned long long* keys1 = (unsigned long long*)alloc(8 * NP1);

  const size_t MB = 1024 * 1024;
  // 16MB region: Gh2/Hh2 gathers (0..8MB); later B2 fp32 (0..4MB) + B2t splits (4..8MB)
  char* regB1 = (char*)alloc(16 * MB);
  unsigned short* Gh2 = (unsigned short*)regB1;
  unsigned short* Hh2 = (unsigned short*)(regB1 + 4 * MB);
  float* B2   = (float*)regB1;
  unsigned short* B2th = (unsigned short*)(regB1 + 4 * MB);
  unsigned short* B2tl = (unsigned short*)(regB1 + 6 * MB);
  float* pscr = (float*)alloc(16 * MB);  // split-K partials

  unsigned short* B1rm = (unsigned short*)alloc(8 * MB);  // packed bf16 (exact)
  unsigned short* B1t  = (unsigned short*)alloc(8 * MB);  // packed bf16 transpose (exact)
  float* res0 = (float*)alloc(4 * MB);
  float* res1 = (float*)alloc(4 * MB);
  float* yreg = (float*)alloc(4 * MB);   // G (4096x128) then y4 (4096x128)
  float* Gspmm = yreg;
  float* outreg = (float*)alloc(2 * MB); // x1s (2048x256) then out2 / out3
  float* x1s = outreg;
  float* out2 = outreg, *out3 = outreg;
  char* ytreg = (char*)alloc(4 * MB);    // Y2t h+l / Y3t h+l
  unsigned short* Y2th = (unsigned short*)ytreg;
  unsigned short* Y2tl = (unsigned short*)(ytreg + 1 * MB);
  unsigned short* Y3th = (unsigned short*)ytreg;
  unsigned short* Y3tl = (unsigned short*)(ytreg + 1 * MB);
  char* xsreg = (char*)alloc(4 * MB);    // x3 h+l -> x4 h+l
  unsigned short* x3h = (unsigned short*)xsreg;
  unsigned short* x3l = (unsigned short*)(xsreg + 2 * MB);
  unsigned short* x4h = (unsigned short*)xsreg;
  unsigned short* x4l = (unsigned short*)(xsreg + 2 * MB);
  unsigned short* xh = (unsigned short*)alloc(1 * MB);   // Gh (4096x128 split)
  unsigned short* xl = (unsigned short*)alloc(1 * MB);
  char* xsm = (char*)alloc(2 * MB);      // x1t h+l -> Z h+l -> x2 h+l
  unsigned short* x1th = (unsigned short*)xsm;
  unsigned short* x1tl = (unsigned short*)(xsm + 1 * MB);
  unsigned short* Zh = (unsigned short*)xsm;
  unsigned short* Zl = (unsigned short*)(xsm + 1 * MB);
  unsigned short* x2h = (unsigned short*)xsm;
  unsigned short* x2l = (unsigned short*)(xsm + 1 * MB);
  unsigned short* Wt0h = (unsigned short*)alloc(256 * 128 * 2);
  unsigned short* Wt0l = (unsigned short*)alloc(256 * 128 * 2);
  unsigned short* Wt1h = (unsigned short*)alloc(512 * 256 * 2);
  unsigned short* Wt1l = (unsigned short*)alloc(512 * 256 * 2);
  unsigned short* Wt2h = (unsigned short*)alloc(512 * 512 * 2);
  unsigned short* Wt2l = (unsigned short*)alloc(512 * 512 * 2);
  unsigned short* Wt3h = (unsigned short*)alloc(256 * 512 * 2);
  unsigned short* Wt3l = (unsigned short*)alloc(256 * 512 * 2);
  unsigned short* Wt4h = (unsigned short*)alloc(128 * 256 * 2);
  unsigned short* Wt4l = (unsigned short*)alloc(128 * 256 * 2);

  hipMemsetAsync(cnts, 0, zero_bytes, stream);

  // graph build
  hist_kernel<<<EE / 256, 256, 0, stream>>>(esrc, edst, cnt_src, cnt_dst, EE);
  scan2<<<2, 1024, 0, stream>>>(cnt_dst, cnt_src, csc_off, csr_off, dis0, NN);
  scatter_kernel<<<EE / 256, 256, 0, stream>>>(esrc, edst, csc_off, csr_off,
                                               fill_dst, fill_src, csc_src, csr_dst, EE);
  pnorm2<<<2, 256, 0, stream>>>(p0, p1, pnrm);
  wconv_all<<<288, 256, 0, stream>>>(w0, w1, w2, w3, w4, Wt0h, Wt0l, Wt1h, Wt1l,
                                     Wt2h, Wt2l, Wt3h, Wt3l, Wt4h, Wt4l);

  // gcn0 (A-first): G = dis ⊙ (M+I)^T (dis ⊙ x); res0 = relu(G W0 + b0)
  spmm_pre<128><<<NN / 4, 256, 0, stream>>>(x, csc_off, csc_src, dis0, Gspmm);
  split_p<<<(NN * 128 / 8) / 256, 256, 0, stream>>>(Gspmm, xh, xl, 128);
  gemm16<4, 1, 1, 128, 1><<<dim3(4, 64), 256, 0, stream>>>(xh, xl, Wt0h, Wt0l,
                                                           NN, 256, nullptr, b0, res0, nullptr, nullptr);

  // pool0
  score_key<<<NN, 256, 0, stream>>>(res0, p0, pnrm + 0, s0, keys0, 256);
  rank_count<<<dim3(NN / 256, NN / 512), 256, 0, stream>>>(keys0, rank0);
  rank_place<<<NN / 256, 256, 0, stream>>>(s0, rank0, NP1, NN, kept0, perm0, vals0, cntk);

  // augment0: packed B1rm directly, sparse deg, packed transpose
  aug_row_p<<<NP1, 256, 0, stream>>>(csr_off, csr_dst, kept0, perm0, B1rm);
  cnt_edges<<<EE / 256, 256, 0, stream>>>(esrc, edst, kept0, cntk, EE);
  deg_gather<<<NP1 / 4, 256, 0, stream>>>(csc_off, csc_src, cntk, perm0, dis1);
  t_pack<<<dim3(32, 32), 256, 0, stream>>>(B1rm, B1t, NP1);

  // gcn1 (A-first): Z = B1^T (dis1 ⊙ x1); res1 = relu(dis1 ⊙ (Z W1) + b1)
  pool_gather_s<<<NP1, 256, 0, stream>>>(res0, perm0, vals0, dis1, x1s, 256);
  tsplit_p<<<(NP1 * 256 / 8) / 256, 256, 0, stream>>>(x1s, x1th, x1tl, NP1, 256);
  gemm16<0, 0, 1, 1024, 2><<<dim3(4, 32, 2), 256, 0, stream>>>(B1t, nullptr, x1th, x1tl,
                                                               NP1, 256, nullptr, nullptr, pscr, nullptr, nullptr);
  ep_zsplit<2><<<(NP1 * 256 / 8) / 256, 256, 0, stream>>>(pscr, Zh, Zl, NP1, 256);
  gemm16<3, 1, 1, 256, 1><<<dim3(8, 32), 256, 0, stream>>>(Zh, Zl, Wt1h, Wt1l,
                                                           NP1, 512, dis1, b1, res1, nullptr, nullptr);

  // pool1
  score_key<<<NP1, 256, 0, stream>>>(res1, p1, pnrm + 1, s1, keys1, 512);
  rank_count<<<dim3(NP1 / 256, NP1 / 512), 256, 0, stream>>>(keys1, rank1);
  rank_place<<<NP1 / 256, 256, 0, stream>>>(s1, rank1, NP2, NP1, kept1, perm1, vals1, nullptr);
  pool_split_p<<<NP2, 64, 0, stream>>>(res1, perm1, vals1, x2h, x2l, 512);

  // augment1: gathered packed operands -> dense exact GEMM (split-K) -> B2 + colsums
  gather2_p<<<dim3((NP2 * NP1 / 8) / 256, 2), 256, 0, stream>>>(B1rm, B1t, perm1, Gh2, Hh2, NP1 >> 5);
  gemm64<0, 0, 512, 4><<<dim3(8, 8, 4), 256, 0, stream>>>(Gh2, nullptr, Hh2, nullptr,
                                                          NP2, NP2, pscr);
  ep_aug_cs<4><<<dim3(NP2 / 256, NP2 / 64), 256, 0, stream>>>(pscr, B2, deg2, NP2);
  dis_from_deg<<<NP2 / 256, 256, 0, stream>>>(deg2, dis2, NP2);
  tsplit_p<<<(NP2 * NP2 / 8) / 256, 256, 0, stream>>>(B2, B2th, B2tl, NP2, NP2);

  // gcn2 (bottleneck, X-first)
  gemm16<2, 1, 1, 512, 1><<<dim3(8, 16), 256, 0, stream>>>(x2h, x2l, Wt2h, Wt2l,
                                                           NP2, 512, dis2, nullptr, nullptr, Y2th, Y2tl);
  gemm16<0, 1, 1, 512, 2><<<dim3(8, 16, 2), 256, 0, stream>>>(B2th, B2tl, Y2th, Y2tl,
                                                              NP2, 512, nullptr, nullptr, pscr, nullptr, nullptr);
  ep3<2><<<(NP2 * 512) / 1024, 256, 0, stream>>>(pscr, dis2, b2, out2, NP2, 512);

  // up1 (X-first: c_out < c_in)
  unpool_split_p<<<(NP1 * 512 / 8) / 256, 256, 0, stream>>>(res1, out2, kept1, x3h, x3l, 512);
  gemm16<2, 1, 1, 512, 1><<<dim3(4, 32), 256, 0, stream>>>(x3h, x3l, Wt3h, Wt3l,
                                                           NP1, 256, dis1, nullptr, nullptr, Y3th, Y3tl);
  gemm64<0, 1, 256, 8><<<dim3(2, 16, 8), 256, 0, stream>>>(B1t, nullptr, Y3th, Y3tl,
                                                           NP1, 256, pscr);
  ep3<8><<<(NP1 * 256) / 1024, 256, 0, stream>>>(pscr, dis1, b3, out3, NP1, 256);

  // up0 (X-first: c_out < c_in)
  unpool_split_p<<<(NN * 256 / 8) / 256, 256, 0, stream>>>(res0, out3, kept0, x4h, x4l, 256);
  gemm16<1, 1, 1, 256, 1><<<dim3(2, 64), 256, 0, stream>>>(x4h, x4l, Wt4h, Wt4l,
                                                           NN, 128, dis0, nullptr, yreg, nullptr, nullptr);
  spmm_gather_v<128><<<NN / 4, 256, 0, stream>>>(yreg, csc_off, csc_src, dis0, b4, out);
}

// Round 11
// 312.097 us; speedup vs baseline: 1.3201x; 1.0889x over previous
//
#include <hip/hip_runtime.h>

#define NN 4096
#define EE 131072
#define NP1 2048
#define NP2 1024

typedef __attribute__((ext_vector_type(8))) __bf16 bf16x8;
typedef __attribute__((ext_vector_type(4))) float f32x4;
typedef __attribute__((ext_vector_type(8))) unsigned short ushort8;

static __device__ inline unsigned short bfbits(__bf16 b) {
  union { __bf16 x; unsigned short u; } c; c.x = b; return c.u;
}
static __device__ inline void split2(float v, unsigned short& h, unsigned short& l) {
  __bf16 hb = (__bf16)v;
  float hf = (float)hb;
  __bf16 lb = (__bf16)(v - hf);
  h = bfbits(hb); l = bfbits(lb);
}

// Packed fragment layout for [R rows][K k] bf16 (R%16==0, K%32==0):
// 16x32 tile (rt,kt); chunk-in-tile = ((k>>3)&3)*16 + (r&15) == MFMA lane id.
static __device__ inline size_t pchunk(int r, int k, int NT) {
  return ((size_t)(r >> 4) * NT + (k >> 5)) * 64 + (((k >> 3) & 3) << 4) + (r & 15);
}

static __device__ inline void tsplit_body(const float* in, unsigned short* oh, unsigned short* ol,
                                          int R, int C, int c) {
  int lane = c & 63, tile = c >> 6;
  int NT = R >> 5;
  int kt = tile % NT, jt = tile / NT;
  int j = jt * 16 + (lane & 15);
  int k = kt * 32 + (lane >> 4) * 8;
  ushort8 hv, lv;
#pragma unroll
  for (int e = 0; e < 8; ++e) {
    unsigned short he, le;
    split2(in[(size_t)(k + e) * C + j], he, le);
    hv[e] = he; lv[e] = le;
  }
  *(ushort8*)&oh[(size_t)c * 8] = hv;
  *(ushort8*)&ol[(size_t)c * 8] = lv;
}

// ---------------- fused prep: edge histogram + weight conversions + p-norms ----------------

__global__ __launch_bounds__(256) void prep_all(
    const int* __restrict__ esrc, const int* __restrict__ edst,
    int* __restrict__ cnt_src, int* __restrict__ cnt_dst,
    const float* w0, const float* w1, const float* w2, const float* w3, const float* w4,
    unsigned short* o0h, unsigned short* o0l, unsigned short* o1h, unsigned short* o1l,
    unsigned short* o2h, unsigned short* o2l, unsigned short* o3h, unsigned short* o3l,
    unsigned short* o4h, unsigned short* o4l,
    const float* p0, const float* p1, float* pnrm) {
  __shared__ float red[4];
  int b = blockIdx.x;
  int tid = threadIdx.x;
  if (b < EE / 256) {
    int e = b * 256 + tid;
    atomicAdd(&cnt_src[esrc[e]], 1);
    atomicAdd(&cnt_dst[edst[e]], 1);
  } else if (b < EE / 256 + 288) {
    int g = (b - EE / 256) * 256 + tid;
    if (g < 4096)        tsplit_body(w0, o0h, o0l, 128, 256, g);
    else if (g < 20480)  tsplit_body(w1, o1h, o1l, 256, 512, g - 4096);
    else if (g < 53248)  tsplit_body(w2, o2h, o2l, 512, 512, g - 20480);
    else if (g < 69632)  tsplit_body(w3, o3h, o3l, 512, 256, g - 53248);
    else                 tsplit_body(w4, o4h, o4l, 256, 128, g - 69632);
  } else {
    int which = b - (EE / 256 + 288);
    const float* p = which ? p1 : p0;
    int C = which ? 512 : 256;
    float acc = 0.f;
    for (int j = tid; j < C; j += 256) { float v = p[j]; acc += v * v; }
    for (int o = 32; o > 0; o >>= 1) acc += __shfl_down(acc, o);
    if ((tid & 63) == 0) red[tid >> 6] = acc;
    __syncthreads();
    if (tid == 0) pnrm[which] = sqrtf(red[0] + red[1] + red[2] + red[3]);
  }
}

// both exclusive scans in one launch; block 0 also emits dis0
__global__ __launch_bounds__(1024) void scan2(const int* __restrict__ cnt_dst,
                                              const int* __restrict__ cnt_src,
                                              int* __restrict__ csc_off, int* __restrict__ csr_off,
                                              float* __restrict__ dis0, int n) {
  __shared__ int tmp[4096];
  const int* in = blockIdx.x ? cnt_src : cnt_dst;
  int* out = blockIdx.x ? csr_off : csc_off;
  int tid = threadIdx.x;
  for (int i = tid; i < n; i += 1024) {
    int v = in[i];
    tmp[i] = v;
    if (blockIdx.x == 0) dis0[i] = rsqrtf((float)v + 1.0f);
  }
  __syncthreads();
  for (int off = 1; off < n; off <<= 1) {
    int v[4];
    int c = 0;
    for (int i = tid; i < n; i += 1024) { v[c++] = (i >= off) ? tmp[i - off] : 0; }
    __syncthreads();
    c = 0;
    for (int i = tid; i < n; i += 1024) { tmp[i] += v[c++]; }
    __syncthreads();
  }
  for (int i = tid; i < n; i += 1024) out[i + 1] = tmp[i];
  if (tid == 0) out[0] = 0;
}

__global__ void scatter_kernel(const int* __restrict__ src, const int* __restrict__ dst,
                               const int* __restrict__ csc_off, const int* __restrict__ csr_off,
                               int* __restrict__ fill_dst, int* __restrict__ fill_src,
                               int* __restrict__ csc_src, int* __restrict__ csr_dst, int E) {
  int e = blockIdx.x * blockDim.x + threadIdx.x;
  if (e < E) {
    int s = src[e], d = dst[e];
    int p = atomicAdd(&fill_dst[d], 1);
    csc_src[csc_off[d] + p] = s;
    int q = atomicAdd(&fill_src[s], 1);
    csr_dst[csr_off[s] + q] = d;
  }
}

// ---------------- scoring / topk ----------------

__global__ void score_key(const float* __restrict__ X, const float* __restrict__ p,
                          const float* __restrict__ pn, float* __restrict__ s,
                          unsigned long long* __restrict__ keys, int C) {
  int i = blockIdx.x;
  int tid = threadIdx.x;
  float acc = 0.f;
  for (int j = tid; j < C; j += 256) acc += X[(size_t)i * C + j] * p[j];
  for (int o = 32; o > 0; o >>= 1) acc += __shfl_down(acc, o);
  __shared__ float red[4];
  if ((tid & 63) == 0) red[tid >> 6] = acc;
  __syncthreads();
  if (tid == 0) {
    float sv = tanhf((red[0] + red[1] + red[2] + red[3]) / pn[0]);
    s[i] = sv;
    unsigned u = __float_as_uint(sv);
    unsigned m = (u & 0x80000000u) ? ~u : (u | 0x80000000u);
    keys[i] = (((unsigned long long)(~m)) << 32) | (unsigned)i;  // desc value, asc index
  }
}

// partial rank: block (bx,by) counts keys[by*512..+512) against candidates [bx*256..+256)
__global__ __launch_bounds__(256) void rank_count(const unsigned long long* __restrict__ keys,
                                                  int* __restrict__ rank) {
  __shared__ unsigned long long kk[512];
  int tid = threadIdx.x;
  int cand = blockIdx.x * 256 + tid;
  int base = blockIdx.y * 512;
  kk[tid] = keys[base + tid];
  kk[tid + 256] = keys[base + tid + 256];
  __syncthreads();
  unsigned long long kc = keys[cand];
  int c = 0;
#pragma unroll 8
  for (int t = 0; t < 512; ++t) c += (kk[t] < kc) ? 1 : 0;
  atomicAdd(&rank[cand], c);
}

// place by rank; optionally emit cntk (1 if kept) for the sparse-deg path
__global__ void rank_place(const float* __restrict__ s, const int* __restrict__ rank, int k, int n,
                           int* __restrict__ kept, int* __restrict__ perm, float* __restrict__ vals,
                           int* __restrict__ cntk) {
  int i = blockIdx.x * blockDim.x + threadIdx.x;
  if (i < n) {
    int r = rank[i];
    int isk = (r < k) ? 1 : 0;
    if (isk) { perm[r] = i; vals[r] = s[i]; kept[i] = r; }
    else kept[i] = -1;
    if (cntk) cntk[i] = isk;
  }
}

// pooled row gather + gate + bf16 split into PACKED layout (unscaled)
__global__ void pool_split_p(const float* __restrict__ X, const int* __restrict__ perm,
                             const float* __restrict__ vals, unsigned short* __restrict__ h,
                             unsigned short* __restrict__ l, int C) {
  int a = blockIdx.x;
  int r = perm[a];
  float v = vals[a];
  int NT = C >> 5;
  for (int j0 = threadIdx.x * 8; j0 < C; j0 += 64 * 8) {
    ushort8 hv, lv;
#pragma unroll
    for (int e = 0; e < 8; ++e) {
      unsigned short he, le;
      split2(X[(size_t)r * C + j0 + e] * v, he, le);
      hv[e] = he; lv[e] = le;
    }
    size_t c = pchunk(a, j0, NT);
    *(ushort8*)&h[c * 8] = hv;
    *(ushort8*)&l[c * 8] = lv;
  }
}

// pool-gather + gate + dis-scale + transpose-split packed ([256 ch][2048 nodes])
__global__ void pool_tsplit_p(const float* __restrict__ X, const int* __restrict__ perm,
                              const float* __restrict__ vals, const float* __restrict__ dis,
                              unsigned short* __restrict__ h, unsigned short* __restrict__ l) {
  int c = blockIdx.x * blockDim.x + threadIdx.x;
  int tile = c >> 6, lno = c & 63;
  int kt = tile & 63, jt = tile >> 6;   // NT = 2048/32 = 64
  int j = jt * 16 + (lno & 15);
  int k0 = kt * 32 + (lno >> 4) * 8;
  ushort8 hv, lv;
#pragma unroll
  for (int e = 0; e < 8; ++e) {
    int node = k0 + e;
    float sc = vals[node] * dis[node];
    float v = X[(size_t)perm[node] * 256 + j] * sc;
    unsigned short he, le;
    split2(v, he, le);
    hv[e] = he; lv[e] = le;
  }
  *(ushort8*)&h[(size_t)c * 8] = hv;
  *(ushort8*)&l[(size_t)c * 8] = lv;
}

// ---------------- augment 0 (fused): sparse 2-path rows + kept-edge counts ----------------

__global__ __launch_bounds__(256) void augcnt(const int* __restrict__ csr_off,
                                              const int* __restrict__ csr_dst,
                                              const int* __restrict__ kept,
                                              const int* __restrict__ perm,
                                              unsigned short* __restrict__ rm,
                                              const int* __restrict__ esrc,
                                              const int* __restrict__ edst,
                                              int* __restrict__ cntk) {
  __shared__ float acc[NP1];
  int b = blockIdx.x;
  if (b < NP1) {
    int ki = b;
    int r = perm[ki];
    for (int t = threadIdx.x; t < NP1; t += 256) acc[t] = 0.f;
    __syncthreads();
    int s = csr_off[r], e = csr_off[r + 1];
    int nm = e - s;
    int wave = threadIdx.x >> 6, lane = threadIdx.x & 63;
    for (int m = wave; m <= nm; m += 4) {
      int k = (m < nm) ? csr_dst[s + m] : r;
      int s2 = csr_off[k], e2 = csr_off[k + 1];
      int n2 = e2 - s2;
      for (int t = lane; t <= n2; t += 64) {
        int j = (t < n2) ? csr_dst[s2 + t] : k;
        int kj = kept[j];
        if (kj >= 0) atomicAdd(&acc[kj], 1.0f);
      }
    }
    __syncthreads();
    if (threadIdx.x == 0) acc[ki] += 1.0f;  // +I on pooled graph
    __syncthreads();
    int tid = threadIdx.x;
    ushort8 hv;
#pragma unroll
    for (int e8 = 0; e8 < 8; ++e8) hv[e8] = bfbits((__bf16)acc[tid * 8 + e8]);
    size_t dst = (((size_t)(ki >> 4)) * 64 + (tid >> 2)) * 64 + (size_t)(tid & 3) * 16 + (ki & 15);
    *(ushort8*)&rm[dst * 8] = hv;
  } else {
    int e = (b - NP1) * 256 + threadIdx.x;
    if (kept[esrc[e]] >= 0) atomicAdd(&cntk[edst[e]], 1);
  }
}

// fused: packed transpose of B1rm (blocks 0..1023) + dis1 from sparse degs (blocks 1024..1535)
__global__ __launch_bounds__(256) void degtp(const unsigned short* __restrict__ in,
                                             unsigned short* __restrict__ outp, int n,
                                             const int* __restrict__ csc_off,
                                             const int* __restrict__ csc_src,
                                             const int* __restrict__ cntk,
                                             const int* __restrict__ perm,
                                             float* __restrict__ dis) {
  __shared__ unsigned short t[64][72];
  int b = blockIdx.x;
  if (b < 1024) {
    int r0 = (b >> 5) * 64, c0 = (b & 31) * 64;
    int NT = n >> 5;
    for (int q = threadIdx.x; q < 512; q += 256) {
      int lt = q >> 6, l = q & 63;
      int rt = lt >> 1, kt2 = lt & 1;
      int r = rt * 16 + (l & 15), k = kt2 * 32 + (l >> 4) * 8;
      ushort8 v = *(const ushort8*)&in[pchunk(r0 + r, c0 + k, NT) * 8];
      *(ushort8*)&t[r][k] = v;
    }
    __syncthreads();
    for (int q = threadIdx.x; q < 512; q += 256) {
      int lt = q >> 6, l = q & 63;
      int jt = lt >> 1, kt2 = lt & 1;
      int j = jt * 16 + (l & 15), k = kt2 * 32 + (l >> 4) * 8;
      ushort8 v;
#pragma unroll
      for (int e = 0; e < 8; ++e) v[e] = t[k + e][j];
      *(ushort8*)&outp[pchunk(c0 + j, r0 + k, NT) * 8] = v;
    }
  } else {
    int bid = b - 1024;
    int wid = threadIdx.x >> 6, lane = threadIdx.x & 63;
    int c = bid * 4 + wid;
    int r = perm[c];
    int s = csc_off[r], e = csc_off[r + 1];
    int sum = 0;
    for (int t2 = s + lane; t2 < e; t2 += 64) sum += cntk[csc_src[t2]];
    for (int o = 32; o > 0; o >>= 1) sum += __shfl_down(sum, o);
    if (lane == 0) dis[c] = rsqrtf((float)(sum + cntk[r] + 1));
  }
}

// ---------------- conversions ----------------

// fp32 row-major [R][K] -> packed bf16 hi/lo
__global__ void split_p(const float* __restrict__ in, unsigned short* __restrict__ h,
                        unsigned short* __restrict__ l, int K) {
  int c = blockIdx.x * blockDim.x + threadIdx.x;
  int lane = c & 63, tile = c >> 6;
  int NT = K >> 5;
  int kt = tile % NT, rt = tile / NT;
  int r = rt * 16 + (lane & 15);
  int k = kt * 32 + (lane >> 4) * 8;
  const float* p = in + (size_t)r * K + k;
  ushort8 hv, lv;
#pragma unroll
  for (int e = 0; e < 8; ++e) {
    unsigned short he, le;
    split2(p[e], he, le);
    hv[e] = he; lv[e] = le;
  }
  *(ushort8*)&h[(size_t)c * 8] = hv;
  *(ushort8*)&l[(size_t)c * 8] = lv;
}

// two packed row-gathers in one launch (blockIdx.y selects)
__global__ void gather2_p(const unsigned short* __restrict__ in0, const unsigned short* __restrict__ in1,
                          const int* __restrict__ perm,
                          unsigned short* __restrict__ out0, unsigned short* __restrict__ out1, int NT) {
  const unsigned short* in = blockIdx.y ? in1 : in0;
  unsigned short* outp = blockIdx.y ? out1 : out0;
  int c = blockIdx.x * blockDim.x + threadIdx.x;
  int lane = c & 63, tile = c >> 6;
  int kt = tile % NT, at = tile / NT;
  int a = at * 16 + (lane & 15);
  int sub = lane >> 4;
  int p = perm[a];
  size_t sc = ((size_t)(p >> 4) * NT + kt) * 64 + sub * 16 + (p & 15);
  *(ushort8*)&outp[(size_t)c * 8] = *(const ushort8*)&in[sc * 8];
}

__global__ void unpool_split_p(const float* __restrict__ res, const float* __restrict__ up,
                               const int* __restrict__ kept, unsigned short* __restrict__ h,
                               unsigned short* __restrict__ l, int C) {
  int c = blockIdx.x * blockDim.x + threadIdx.x;
  int lane = c & 63, tile = c >> 6;
  int NT = C >> 5;
  int kt = tile % NT, rt = tile / NT;
  int r = rt * 16 + (lane & 15);
  int j0 = kt * 32 + (lane >> 4) * 8;
  int kv = kept[r];
  ushort8 hv, lv;
#pragma unroll
  for (int e = 0; e < 8; ++e) {
    float v = res[(size_t)r * C + j0 + e];
    if (kv >= 0) v += up[(size_t)kv * C + j0 + e];
    unsigned short he, le;
    split2(v, he, le);
    hv[e] = he; lv[e] = le;
  }
  *(ushort8*)&h[(size_t)c * 8] = hv;
  *(ushort8*)&l[(size_t)c * 8] = lv;
}

// ---------------- sparse aggregation ----------------

// A-first spmm: G[c][j] = dis[c] * ( dis[c]*x[c][j] + sum_src dis[src]*x[src][j] )
template <int C>
__global__ __launch_bounds__(256) void spmm_pre(const float* __restrict__ X,
                                                const int* __restrict__ off,
                                                const int* __restrict__ srcs,
                                                const float* __restrict__ dis,
                                                float* __restrict__ out) {
  constexpr int VEC = C / 64;
  int w = threadIdx.x >> 6, lane = threadIdx.x & 63;
  int c = blockIdx.x * 4 + w;
  int j = lane * VEC;
  float dc = dis[c];
  float acc[VEC];
  const float* p = X + (size_t)c * C + j;
#pragma unroll
  for (int u = 0; u < VEC; ++u) acc[u] = dc * p[u];
  int s = off[c], e = off[c + 1];
  for (int t = s; t < e; ++t) {
    int sr = srcs[t];
    float ds = dis[sr];
    const float* q = X + (size_t)sr * C + j;
#pragma unroll
    for (int u = 0; u < VEC; ++u) acc[u] += ds * q[u];
  }
  float* o = out + (size_t)c * C + j;
#pragma unroll
  for (int u = 0; u < VEC; ++u) o[u] = dc * acc[u];
}

// X-first spmm (gcn4): out = relu(dis[c]*(sum of pre-scaled rows) + bias)
template <int C>
__global__ __launch_bounds__(256) void spmm_gather_v(const float* __restrict__ Y,
                                                     const int* __restrict__ off,
                                                     const int* __restrict__ srcs,
                                                     const float* __restrict__ dis,
                                                     const float* __restrict__ bias,
                                                     float* __restrict__ out) {
  constexpr int VEC = C / 64;
  int w = threadIdx.x >> 6, lane = threadIdx.x & 63;
  int c = blockIdx.x * 4 + w;
  int j = lane * VEC;
  float acc[VEC];
  const float* p = Y + (size_t)c * C + j;
#pragma unroll
  for (int u = 0; u < VEC; ++u) acc[u] = p[u];
  int s = off[c], e = off[c + 1];
  for (int t = s; t < e; ++t) {
    const float* q = Y + (size_t)srcs[t] * C + j;
#pragma unroll
    for (int u = 0; u < VEC; ++u) acc[u] += q[u];
  }
  float d = dis[c];
  float* o = out + (size_t)c * C + j;
#pragma unroll
  for (int u = 0; u < VEC; ++u) o[u] = fmaxf(d * acc[u] + bias[j + u], 0.0f);
}

// ---------------- split-K combines ----------------

// out = relu(rs*(sum of S partials) + bias); RSQ: rs -> rsqrt(rs)
template <int S, int RSQ>
__global__ void ep3(const float* __restrict__ p, const float* __restrict__ rs,
                    const float* __restrict__ bias, float* __restrict__ outp, int M, int N) {
  int idx = blockIdx.x * blockDim.x + threadIdx.x;
  int j4 = (idx * 4) % N, i = (idx * 4) / N;
  float4 a = {0.f, 0.f, 0.f, 0.f};
#pragma unroll
  for (int s = 0; s < S; ++s) {
    float4 b = *(const float4*)(p + ((size_t)s * M + i) * N + j4);
    a.x += b.x; a.y += b.y; a.z += b.z; a.w += b.w;
  }
  float r = rs[i];
  if (RSQ) r = rsqrtf(r);
  float4 o;
  o.x = fmaxf(r * a.x + bias[j4 + 0], 0.f);
  o.y = fmaxf(r * a.y + bias[j4 + 1], 0.f);
  o.z = fmaxf(r * a.z + bias[j4 + 2], 0.f);
  o.w = fmaxf(r * a.w + bias[j4 + 3], 0.f);
  *(float4*)(outp + (size_t)i * N + j4) = o;
}

// combine S partials -> packed bf16 hi/lo row-major (for Z = B1^T Xs)
template <int S>
__global__ void ep_zsplit(const float* __restrict__ p, unsigned short* __restrict__ h,
                          unsigned short* __restrict__ l, int M, int N) {
  int t = blockIdx.x * blockDim.x + threadIdx.x;
  int tile = t >> 6, w = t & 63;
  int NT = N >> 5;
  int rt = tile / NT, kt = tile % NT;
  int r = rt * 16 + (w & 15);
  int k = kt * 32 + (w >> 4) * 8;
  const float* p0 = p + (size_t)r * N + k;
  ushort8 hv, lv;
#pragma unroll
  for (int e = 0; e < 8; ++e) {
    float v = p0[e];
#pragma unroll
    for (int s = 1; s < S; ++s) v += p0[(size_t)s * M * N + e];
    unsigned short he, le;
    split2(v, he, le);
    hv[e] = he; lv[e] = le;
  }
  *(ushort8*)&h[(size_t)t * 8] = hv;
  *(ushort8*)&l[(size_t)t * 8] = lv;
}

// combine S partials (+I) -> PACKED transpose-split B2t directly, + column sums into deg
template <int S>
__global__ void ep_aug_cs2(const float* __restrict__ p, unsigned short* __restrict__ th,
                           unsigned short* __restrict__ tl, float* __restrict__ deg, int n) {
  int c = blockIdx.x * 256 + threadIdx.x;   // column of B2 == row of B2t
  int r0 = blockIdx.y * 64;                 // rows of B2 == k of B2t
  int NT = n >> 5;
  float cs = 0.f;
  for (int g = 0; g < 8; ++g) {
    float vbuf[8];
#pragma unroll
    for (int e = 0; e < 8; ++e) {
      int r = r0 + g * 8 + e;
      float v = 0.f;
#pragma unroll
      for (int s = 0; s < S; ++s) v += p[((size_t)s * n + r) * n + c];
      if (r == c) v += 1.0f;
      vbuf[e] = v;
      cs += v;
    }
    ushort8 hv, lv;
#pragma unroll
    for (int e = 0; e < 8; ++e) {
      unsigned short he, le;
      split2(vbuf[e], he, le);
      hv[e] = he; lv[e] = le;
    }
    size_t ch = pchunk(c, r0 + g * 8, NT);
    *(ushort8*)&th[ch * 8] = hv;
    *(ushort8*)&tl[ch * 8] = lv;
  }
  atomicAdd(&deg[c], cs);
}

// ---------------- bf16-split MFMA GEMM, 32x32/wave ----------------
// S>1: partial to C + z*M*N. S==1 EPI: 0 plain; 1 rowscale; 2 rowscale+packed-T-split;
// 3 rowscale+bias+relu; 4 bias+relu. RSQ: rs -> rsqrt(rs).
template <int EPI, int AL, int BL, int KK, int S, int RSQ>
__global__ __launch_bounds__(256) void gemm16(
    const unsigned short* __restrict__ Ah, const unsigned short* __restrict__ Al,
    const unsigned short* __restrict__ Bh, const unsigned short* __restrict__ Bl,
    int M, int N, const float* __restrict__ rs, const float* __restrict__ bias,
    float* __restrict__ C, unsigned short* __restrict__ Th, unsigned short* __restrict__ Tl) {
  static_assert(KK % 32 == 0, "K");
  constexpr int KSTEPS = KK / 32;
  const int NT = (KK * S) >> 5;
  const int gx = gridDim.x;
  int id = blockIdx.y * gx + blockIdx.x;
  int cpx = (gx * gridDim.y) >> 3;
  int sid = (id & 7) * cpx + (id >> 3);
  const int bx = sid % gx, by = sid / gx;
  const int z = (S > 1) ? blockIdx.z : 0;
  const int wid = threadIdx.x >> 6, lane = threadIdx.x & 63;
  const int i0 = by * 64 + (wid >> 1) * 32;
  const int j0 = bx * 64 + (wid & 1) * 32;
  const int lr = lane & 15, lk = lane >> 4;
  size_t aoff[2], boff[2];
#pragma unroll
  for (int t = 0; t < 2; ++t) {
    aoff[t] = ((size_t)((i0 >> 4) + t) * NT + z * (KK >> 5)) * 512 + lane * 8;
    boff[t] = ((size_t)((j0 >> 4) + t) * NT + z * (KK >> 5)) * 512 + lane * 8;
  }
  const f32x4 zf = {0.f, 0.f, 0.f, 0.f};
  f32x4 acc[2][2];
  acc[0][0] = zf; acc[0][1] = zf; acc[1][0] = zf; acc[1][1] = zf;

  bf16x8 ahf[4][2], bhf[4][2], alf[4][2], blf[4][2];
  auto loadk = [&](int kk, int b) {
    size_t o = (size_t)kk * 512;
    ahf[b][0] = *(const bf16x8*)(Ah + aoff[0] + o);
    ahf[b][1] = *(const bf16x8*)(Ah + aoff[1] + o);
    bhf[b][0] = *(const bf16x8*)(Bh + boff[0] + o);
    bhf[b][1] = *(const bf16x8*)(Bh + boff[1] + o);
    if constexpr (AL) {
      alf[b][0] = *(const bf16x8*)(Al + aoff[0] + o);
      alf[b][1] = *(const bf16x8*)(Al + aoff[1] + o);
    }
    if constexpr (BL) {
      blf[b][0] = *(const bf16x8*)(Bl + boff[0] + o);
      blf[b][1] = *(const bf16x8*)(Bl + boff[1] + o);
    }
  };
  auto domm = [&](int b) {
#pragma unroll
    for (int am = 0; am < 2; ++am)
#pragma unroll
      for (int bn = 0; bn < 2; ++bn) {
        acc[am][bn] = __builtin_amdgcn_mfma_f32_16x16x32_bf16(ahf[b][am], bhf[b][bn], acc[am][bn], 0, 0, 0);
        if constexpr (BL)
          acc[am][bn] = __builtin_amdgcn_mfma_f32_16x16x32_bf16(ahf[b][am], blf[b][bn], acc[am][bn], 0, 0, 0);
        if constexpr (AL)
          acc[am][bn] = __builtin_amdgcn_mfma_f32_16x16x32_bf16(alf[b][am], bhf[b][bn], acc[am][bn], 0, 0, 0);
      }
  };

  loadk(0, 0);
  if constexpr (KSTEPS > 1) loadk(1, 1);
  if constexpr (KSTEPS > 2) loadk(2, 2);
#pragma unroll
  for (int kk = 0; kk < KSTEPS; ++kk) {
    const int cur = kk & 3;
    if (kk + 3 < KSTEPS) loadk(kk + 3, (cur + 3) & 3);
    domm(cur);
  }

#pragma unroll
  for (int am = 0; am < 2; ++am)
#pragma unroll
    for (int bn = 0; bn < 2; ++bn) {
      int ib = i0 + 16 * am + lk * 4;
      int j = j0 + 16 * bn + lr;
      f32x4 a = acc[am][bn];
      if constexpr (S > 1) {
#pragma unroll
        for (int r = 0; r < 4; ++r) C[((size_t)z * M + ib + r) * N + j] = a[r];
      } else if constexpr (EPI == 0) {
#pragma unroll
        for (int r = 0; r < 4; ++r) C[(size_t)(ib + r) * N + j] = a[r];
      } else if constexpr (EPI == 1) {
#pragma unroll
        for (int r = 0; r < 4; ++r) {
          float rsv = rs[ib + r];
          if (RSQ) rsv = rsqrtf(rsv);
          C[(size_t)(ib + r) * N + j] = rsv * a[r];
        }
      } else if constexpr (EPI == 2) {
        unsigned long long hp = 0, lp = 0;
#pragma unroll
        for (int r = 0; r < 4; ++r) {
          float rsv = rs[ib + r];
          if (RSQ) rsv = rsqrtf(rsv);
          unsigned short hv, lv;
          split2(rsv * a[r], hv, lv);
          hp |= ((unsigned long long)hv) << (16 * r);
          lp |= ((unsigned long long)lv) << (16 * r);
        }
        size_t c = pchunk(j, ib, M >> 5);
        *(unsigned long long*)&Th[c * 8 + (ib & 7)] = hp;
        *(unsigned long long*)&Tl[c * 8 + (ib & 7)] = lp;
      } else if constexpr (EPI == 3) {
#pragma unroll
        for (int r = 0; r < 4; ++r) {
          float rsv = rs[ib + r];
          if (RSQ) rsv = rsqrtf(rsv);
          C[(size_t)(ib + r) * N + j] = fmaxf(rsv * a[r] + bias[j], 0.0f);
        }
      } else {
#pragma unroll
        for (int r = 0; r < 4; ++r)
          C[(size_t)(ib + r) * N + j] = fmaxf(a[r] + bias[j], 0.0f);
      }
    }
}

// ---------------- bf16-split MFMA GEMM, 64x64/wave (split-K partials) ----------------
template <int AL, int BL, int KK, int S>
__global__ __launch_bounds__(256) void gemm64(
    const unsigned short* __restrict__ Ah, const unsigned short* __restrict__ Al,
    const unsigned short* __restrict__ Bh, const unsigned short* __restrict__ Bl,
    int M, int N, float* __restrict__ C) {
  static_assert(KK % 32 == 0, "K");
  constexpr int KSTEPS = KK / 32;
  const int NT = (KK * S) >> 5;
  const int gx = gridDim.x;
  int id = blockIdx.y * gx + blockIdx.x;
  int cpx = (gx * gridDim.y) >> 3;
  int sid = (id & 7) * cpx + (id >> 3);
  const int bx = sid % gx, by = sid / gx;
  const int z = blockIdx.z;
  const int wid = threadIdx.x >> 6, lane = threadIdx.x & 63;
  const int i0 = by * 128 + (wid >> 1) * 64;
  const int j0 = bx * 128 + (wid & 1) * 64;
  const int lr = lane & 15, lk = lane >> 4;
  size_t aoff[4], boff[4];
#pragma unroll
  for (int t = 0; t < 4; ++t) {
    aoff[t] = ((size_t)((i0 >> 4) + t) * NT + z * (KK >> 5)) * 512 + lane * 8;
    boff[t] = ((size_t)((j0 >> 4) + t) * NT + z * (KK >> 5)) * 512 + lane * 8;
  }
  const f32x4 zf = {0.f, 0.f, 0.f, 0.f};
  f32x4 acc[4][4];
#pragma unroll
  for (int a = 0; a < 4; ++a)
#pragma unroll
    for (int b = 0; b < 4; ++b) acc[a][b] = zf;

  bf16x8 ahf[2][4], bhf[2][4], alf[2][4], blf[2][4];
  auto loadk = [&](int kk, int b) {
    size_t o = (size_t)kk * 512;
#pragma unroll
    for (int t = 0; t < 4; ++t) {
      ahf[b][t] = *(const bf16x8*)(Ah + aoff[t] + o);
      bhf[b][t] = *(const bf16x8*)(Bh + boff[t] + o);
      if constexpr (AL) alf[b][t] = *(const bf16x8*)(Al + aoff[t] + o);
      if constexpr (BL) blf[b][t] = *(const bf16x8*)(Bl + boff[t] + o);
    }
  };
  auto domm = [&](int b) {
#pragma unroll
    for (int am = 0; am < 4; ++am)
#pragma unroll
      for (int bn = 0; bn < 4; ++bn) {
        acc[am][bn] = __builtin_amdgcn_mfma_f32_16x16x32_bf16(ahf[b][am], bhf[b][bn], acc[am][bn], 0, 0, 0);
        if constexpr (BL)
          acc[am][bn] = __builtin_amdgcn_mfma_f32_16x16x32_bf16(ahf[b][am], blf[b][bn], acc[am][bn], 0, 0, 0);
        if constexpr (AL)
          acc[am][bn] = __builtin_amdgcn_mfma_f32_16x16x32_bf16(alf[b][am], bhf[b][bn], acc[am][bn], 0, 0, 0);
      }
  };

  loadk(0, 0);
#pragma unroll
  for (int kk = 0; kk < KSTEPS; ++kk) {
    const int cur = kk & 1;
    if (kk + 1 < KSTEPS) loadk(kk + 1, cur ^ 1);
    domm(cur);
  }

#pragma unroll
  for (int am = 0; am < 4; ++am)
#pragma unroll
    for (int bn = 0; bn < 4; ++bn) {
      int ib = i0 + 16 * am + lk * 4;
      int j = j0 + 16 * bn + lr;
      f32x4 a = acc[am][bn];
#pragma unroll
      for (int r = 0; r < 4; ++r) C[((size_t)z * M + ib + r) * N + j] = a[r];
    }
}

// ---------------- launch ----------------

extern "C" void kernel_launch(void* const* d_in, const int* in_sizes, int n_in,
                              void* d_out, int out_size, void* d_ws, size_t ws_size,
                              hipStream_t stream) {
  (void)in_sizes; (void)n_in; (void)out_size; (void)ws_size;
  const float* x  = (const float*)d_in[0];
  const int* ei   = (const int*)d_in[1];
  const int* esrc = ei;
  const int* edst = ei + EE;
  const float* w0 = (const float*)d_in[2];
  const float* b0 = (const float*)d_in[3];
  const float* w1 = (const float*)d_in[4];
  const float* b1 = (const float*)d_in[5];
  const float* w2 = (const float*)d_in[6];
  const float* b2 = (const float*)d_in[7];
  const float* w3 = (const float*)d_in[8];
  const float* b3 = (const float*)d_in[9];
  const float* w4 = (const float*)d_in[10];
  const float* b4 = (const float*)d_in[11];
  const float* p0 = (const float*)d_in[12];
  const float* p1 = (const float*)d_in[13];
  float* out = (float*)d_out;

  char* ws = (char*)d_ws;
  size_t off = 0;
  auto alloc = [&](size_t b) { void* p = ws + off; off += (b + 255) & ~(size_t)255; return p; };

  int* csc_off = (int*)alloc(4 * (NN + 1));
  int* csr_off = (int*)alloc(4 * (NN + 1));
  int* csc_src = (int*)alloc(4 * EE);
  int* csr_dst = (int*)alloc(4 * EE);

  // zeroed region: 4 count arrays + deg2 + rank0 + rank1
  size_t zero_bytes = 4 * NN * 4 + 4 * NP2 + 4 * NN + 4 * NP1;
  int* cnts    = (int*)alloc(zero_bytes);
  int* cnt_dst = cnts;
  int* cnt_src = cnts + NN;
  int* fill_dst = cnts + 2 * NN;
  int* fill_src = cnts + 3 * NN;
  float* deg2 = (float*)(cnts + 4 * NN);
  int* rank0 = (int*)(deg2 + NP2);
  int* rank1 = rank0 + NN;

  int* cntk  = (int*)alloc(4 * NN);
  int* kept0 = (int*)alloc(4 * NN);
  int* perm0 = (int*)alloc(4 * NP1);
  int* kept1 = (int*)alloc(4 * NP1);
  int* perm1 = (int*)alloc(4 * NP2);
  float* dis0 = (float*)alloc(4 * NN);
  float* dis1 = (float*)alloc(4 * NP1);
  float* pnrm = (float*)alloc(8);
  float* s0   = (float*)alloc(4 * NN);
  float* vals0 = (float*)alloc(4 * NP1);
  float* s1   = (float*)alloc(4 * NP1);
  float* vals1 = (float*)alloc(4 * NP2);
  unsigned long long* keys0 = (unsigned long long*)alloc(8 * NN);
  unsigned long long* keys1 = (unsigned long long*)alloc(8 * NP1);

  const size_t MB = 1024 * 1024;
  // 16MB region: Gh2/Hh2 gathers (0..8MB); later B2t splits (4..8MB, over dead Hh2)
  char* regB1 = (char*)alloc(16 * MB);
  unsigned short* Gh2 = (unsigned short*)regB1;
  unsigned short* Hh2 = (unsigned short*)(regB1 + 4 * MB);
  unsigned short* B2th = (unsigned short*)(regB1 + 4 * MB);
  unsigned short* B2tl = (unsigned short*)(regB1 + 6 * MB);
  float* pscr = (float*)alloc(16 * MB);  // split-K partials

  unsigned short* B1rm = (unsigned short*)alloc(8 * MB);  // packed bf16 (exact)
  unsigned short* B1t  = (unsigned short*)alloc(8 * MB);  // packed bf16 transpose (exact)
  float* res0 = (float*)alloc(4 * MB);
  float* res1 = (float*)alloc(4 * MB);
  float* yreg = (float*)alloc(4 * MB);   // G (4096x128) then y4 (4096x128)
  float* Gspmm = yreg;
  float* outreg = (float*)alloc(2 * MB); // out2 (1024x512) then out3 (2048x256)
  float* out2 = outreg, *out3 = outreg;
  char* ytreg = (char*)alloc(4 * MB);    // Y2t h+l / Y3t h+l
  unsigned short* Y2th = (unsigned short*)ytreg;
  unsigned short* Y2tl = (unsigned short*)(ytreg + 1 * MB);
  unsigned short* Y3th = (unsigned short*)ytreg;
  unsigned short* Y3tl = (unsigned short*)(ytreg + 1 * MB);
  char* xsreg = (char*)alloc(4 * MB);    // x3 h+l -> x4 h+l
  unsigned short* x3h = (unsigned short*)xsreg;
  unsigned short* x3l = (unsigned short*)(xsreg + 2 * MB);
  unsigned short* x4h = (unsigned short*)xsreg;
  unsigned short* x4l = (unsigned short*)(xsreg + 2 * MB);
  unsigned short* xh = (unsigned short*)alloc(1 * MB);   // Gh (4096x128 split)
  unsigned short* xl = (unsigned short*)alloc(1 * MB);
  char* xsm = (char*)alloc(2 * MB);      // x1t h+l -> Z h+l -> x2 h+l
  unsigned short* x1th = (unsigned short*)xsm;
  unsigned short* x1tl = (unsigned short*)(xsm + 1 * MB);
  unsigned short* Zh = (unsigned short*)xsm;
  unsigned short* Zl = (unsigned short*)(xsm + 1 * MB);
  unsigned short* x2h = (unsigned short*)xsm;
  unsigned short* x2l = (unsigned short*)(xsm + 1 * MB);
  unsigned short* Wt0h = (unsigned short*)alloc(256 * 128 * 2);
  unsigned short* Wt0l = (unsigned short*)alloc(256 * 128 * 2);
  unsigned short* Wt1h = (unsigned short*)alloc(512 * 256 * 2);
  unsigned short* Wt1l = (unsigned short*)alloc(512 * 256 * 2);
  unsigned short* Wt2h = (unsigned short*)alloc(512 * 512 * 2);
  unsigned short* Wt2l = (unsigned short*)alloc(512 * 512 * 2);
  unsigned short* Wt3h = (unsigned short*)alloc(256 * 512 * 2);
  unsigned short* Wt3l = (unsigned short*)alloc(256 * 512 * 2);
  unsigned short* Wt4h = (unsigned short*)alloc(128 * 256 * 2);
  unsigned short* Wt4l = (unsigned short*)alloc(128 * 256 * 2);

  hipMemsetAsync(cnts, 0, zero_bytes, stream);

  // graph build + weight conversions + p-norms (1 fused launch after memset)
  prep_all<<<EE / 256 + 288 + 2, 256, 0, stream>>>(
      esrc, edst, cnt_src, cnt_dst, w0, w1, w2, w3, w4,
      Wt0h, Wt0l, Wt1h, Wt1l, Wt2h, Wt2l, Wt3h, Wt3l, Wt4h, Wt4l, p0, p1, pnrm);
  scan2<<<2, 1024, 0, stream>>>(cnt_dst, cnt_src, csc_off, csr_off, dis0, NN);
  scatter_kernel<<<EE / 256, 256, 0, stream>>>(esrc, edst, csc_off, csr_off,
                                               fill_dst, fill_src, csc_src, csr_dst, EE);

  // gcn0 (A-first): G = dis ⊙ (M+I)^T (dis ⊙ x); res0 = relu(G W0 + b0)
  spmm_pre<128><<<NN / 4, 256, 0, stream>>>(x, csc_off, csc_src, dis0, Gspmm);
  split_p<<<(NN * 128 / 8) / 256, 256, 0, stream>>>(Gspmm, xh, xl, 128);
  gemm16<4, 1, 1, 128, 1, 0><<<dim3(4, 64), 256, 0, stream>>>(xh, xl, Wt0h, Wt0l,
                                                              NN, 256, nullptr, b0, res0, nullptr, nullptr);

  // pool0
  score_key<<<NN, 256, 0, stream>>>(res0, p0, pnrm + 0, s0, keys0, 256);
  rank_count<<<dim3(NN / 256, NN / 512), 256, 0, stream>>>(keys0, rank0);
  rank_place<<<NN / 256, 256, 0, stream>>>(s0, rank0, NP1, NN, kept0, perm0, vals0, cntk);

  // augment0 (fused): packed B1rm rows + kept-edge counts; then transpose + dis1 (fused)
  augcnt<<<NP1 + EE / 256, 256, 0, stream>>>(csr_off, csr_dst, kept0, perm0, B1rm,
                                             esrc, edst, cntk);
  degtp<<<1024 + NP1 / 4, 256, 0, stream>>>(B1rm, B1t, NP1, csc_off, csc_src, cntk, perm0, dis1);

  // gcn1 (A-first): Z = B1^T (dis1 ⊙ x1); res1 = relu(dis1 ⊙ (Z W1) + b1)
  pool_tsplit_p<<<(NP1 * 256 / 8) / 256, 256, 0, stream>>>(res0, perm0, vals0, dis1, x1th, x1tl);
  gemm16<0, 0, 1, 1024, 2, 0><<<dim3(4, 32, 2), 256, 0, stream>>>(B1t, nullptr, x1th, x1tl,
                                                                  NP1, 256, nullptr, nullptr, pscr, nullptr, nullptr);
  ep_zsplit<2><<<(NP1 * 256 / 8) / 256, 256, 0, stream>>>(pscr, Zh, Zl, NP1, 256);
  gemm16<3, 1, 1, 256, 1, 0><<<dim3(8, 32), 256, 0, stream>>>(Zh, Zl, Wt1h, Wt1l,
                                                              NP1, 512, dis1, b1, res1, nullptr, nullptr);

  // pool1
  score_key<<<NP1, 256, 0, stream>>>(res1, p1, pnrm + 1, s1, keys1, 512);
  rank_count<<<dim3(NP1 / 256, NP1 / 512), 256, 0, stream>>>(keys1, rank1);
  rank_place<<<NP1 / 256, 256, 0, stream>>>(s1, rank1, NP2, NP1, kept1, perm1, vals1, nullptr);
  pool_split_p<<<NP2, 64, 0, stream>>>(res1, perm1, vals1, x2h, x2l, 512);

  // augment1: gathered packed operands -> dense exact GEMM (split-K) -> packed B2t + colsums
  gather2_p<<<dim3((NP2 * NP1 / 8) / 256, 2), 256, 0, stream>>>(B1rm, B1t, perm1, Gh2, Hh2, NP1 >> 5);
  gemm64<0, 0, 512, 4><<<dim3(8, 8, 4), 256, 0, stream>>>(Gh2, nullptr, Hh2, nullptr,
                                                          NP2, NP2, pscr);
  ep_aug_cs2<4><<<dim3(NP2 / 256, NP2 / 64), 256, 0, stream>>>(pscr, B2th, B2tl, deg2, NP2);

  // gcn2 (bottleneck, X-first); dis2 = rsqrt(deg2) folded into epilogues
  gemm16<2, 1, 1, 512, 1, 1><<<dim3(8, 16), 256, 0, stream>>>(x2h, x2l, Wt2h, Wt2l,
                                                              NP2, 512, deg2, nullptr, nullptr, Y2th, Y2tl);
  gemm16<0, 1, 1, 512, 2, 0><<<dim3(8, 16, 2), 256, 0, stream>>>(B2th, B2tl, Y2th, Y2tl,
                                                                 NP2, 512, nullptr, nullptr, pscr, nullptr, nullptr);
  ep3<2, 1><<<(NP2 * 512) / 1024, 256, 0, stream>>>(pscr, deg2, b2, out2, NP2, 512);

  // up1 (X-first: c_out < c_in)
  unpool_split_p<<<(NP1 * 512 / 8) / 256, 256, 0, stream>>>(res1, out2, kept1, x3h, x3l, 512);
  gemm16<2, 1, 1, 512, 1, 0><<<dim3(4, 32), 256, 0, stream>>>(x3h, x3l, Wt3h, Wt3l,
                                                              NP1, 256, dis1, nullptr, nullptr, Y3th, Y3tl);
  gemm64<0, 1, 256, 8><<<dim3(2, 16, 8), 256, 0, stream>>>(B1t, nullptr, Y3th, Y3tl,
                                                           NP1, 256, pscr);
  ep3<8, 0><<<(NP1 * 256) / 1024, 256, 0, stream>>>(pscr, dis1, b3, out3, NP1, 256);

  // up0 (X-first: c_out < c_in)
  unpool_split_p<<<(NN * 256 / 8) / 256, 256, 0, stream>>>(res0, out3, kept0, x4h, x4l, 256);
  gemm16<1, 1, 1, 256, 1, 0><<<dim3(2, 64), 256, 0, stream>>>(x4h, x4l, Wt4h, Wt4l,
                                                              NN, 128, dis0, nullptr, yreg, nullptr, nullptr);
  spmm_gather_v<128><<<NN / 4, 256, 0, stream>>>(yreg, csc_off, csc_src, dis0, b4, out);
}